// Round 1
// baseline (662.982 us; speedup 1.0000x reference)
//
#include <hip/hip_runtime.h>
#include <cstdint>

typedef unsigned short u16;
typedef __bf16 bf16_t;
typedef bf16_t bf16x8 __attribute__((ext_vector_type(8)));
typedef float f32x4 __attribute__((ext_vector_type(4)));

__device__ __forceinline__ float b2f(u16 v) {
  union { uint32_t u; float f; } c; c.u = ((uint32_t)v) << 16; return c.f;
}
__device__ __forceinline__ u16 f2b(float f) {
  union { float f; uint32_t u; } c; c.f = f;
  uint32_t lsb = (c.u >> 16) & 1u;
  return (u16)((c.u + 0x7fffu + lsb) >> 16);
}
__device__ __forceinline__ uint4 pack8(f32x4 a, f32x4 b) {
  union { uint4 v; u16 s[8]; } r;
  r.s[0] = f2b(a[0]); r.s[1] = f2b(a[1]); r.s[2] = f2b(a[2]); r.s[3] = f2b(a[3]);
  r.s[4] = f2b(b[0]); r.s[5] = f2b(b[1]); r.s[6] = f2b(b[2]); r.s[7] = f2b(b[3]);
  return r.v;
}

// ---------------- transpose f32 (R,C) -> bf16 (C,R) ----------------
__global__ __launch_bounds__(256) void transpose_f2b(const float* __restrict__ in,
                                                     u16* __restrict__ out, int R, int C) {
  __shared__ __align__(16) u16 tile[32][33];
  int tx = threadIdx.x & 31, ty = threadIdx.x >> 5;
  int c0 = blockIdx.x * 32, r0 = blockIdx.y * 32;
#pragma unroll
  for (int i = 0; i < 4; ++i) {
    int r = r0 + ty + i * 8, c = c0 + tx;
    if (r < R && c < C) tile[ty + i * 8][tx] = f2b(in[(size_t)r * C + c]);
  }
  __syncthreads();
#pragma unroll
  for (int i = 0; i < 4; ++i) {
    int oc = c0 + ty + i * 8, orr = r0 + tx;
    if (oc < C && orr < R) out[(size_t)oc * R + orr] = tile[tx][ty + i * 8];
  }
}

// ---------------- VT[b][d][j] from kvb[b][j][64+d] (bf16) ----------------
__global__ __launch_bounds__(256) void vt_kernel(const u16* __restrict__ kvb, u16* __restrict__ VT) {
  __shared__ __align__(16) u16 tile[32][33];
  int tx = threadIdx.x & 31, ty = threadIdx.x >> 5;
  int j0 = blockIdx.x * 32, d0 = blockIdx.y * 32, b = blockIdx.z;
#pragma unroll
  for (int i = 0; i < 4; ++i) {
    int j = j0 + ty + i * 8, d = d0 + tx;
    tile[ty + i * 8][tx] = kvb[((size_t)b * 4096 + j) * 128 + 64 + d];
  }
  __syncthreads();
#pragma unroll
  for (int i = 0; i < 4; ++i) {
    int d = d0 + ty + i * 8, j = j0 + tx;
    VT[((size_t)b * 64 + d) * 4096 + j] = tile[tx][ty + i * 8];
  }
}

// ---------------- WgT[n,k]=g[k]*WcT[n,k]; u[n]=sum g*Wc; w[n]=sum b*Wc ----------------
__global__ __launch_bounds__(256) void prep_wg(const u16* __restrict__ WcT, const float* __restrict__ g,
                                               const float* __restrict__ b, u16* __restrict__ WgT,
                                               float* __restrict__ ucol, float* __restrict__ wcol) {
  int n = blockIdx.x * 4 + (threadIdx.x >> 6);
  int lane = threadIdx.x & 63;
  const u16* src = WcT + (size_t)n * 1024;
  u16* dst = WgT + (size_t)n * 1024;
  float su = 0.f, sw = 0.f;
  for (int k = lane; k < 1024; k += 64) {
    float wc = b2f(src[k]);
    float wg = g[k] * wc;
    dst[k] = f2b(wg);
    su += wg;
    sw += b[k] * wc;
  }
#pragma unroll
  for (int off = 32; off >= 1; off >>= 1) {
    su += __shfl_xor(su, off, 64);
    sw += __shfl_xor(sw, off, 64);
  }
  if (lane == 0) { ucol[n] = su; wcol[n] = sw; }
}

// ---------------- row layernorm (ncols=768): 1 wave/row ----------------
template <bool XF32, bool RES>
__global__ __launch_bounds__(256) void row_ln(const void* __restrict__ xv, const float* __restrict__ g,
                                              const float* __restrict__ bta, u16* __restrict__ outb,
                                              float* __restrict__ outf,
                                              const float* __restrict__ resid,
                                              const float* __restrict__ gatep) {
  int row = blockIdx.x * 4 + (threadIdx.x >> 6);
  int lane = threadIdx.x & 63;
  const u16* xb = (const u16*)xv + (size_t)row * 768;
  const float* xf = (const float*)xv + (size_t)row * 768;
  float v[12];
#pragma unroll
  for (int it = 0; it < 3; ++it) {
    int c = (lane + it * 64) * 4;
    if (XF32) {
      f32x4 d = *(const f32x4*)(xf + c);
      v[it * 4 + 0] = d[0]; v[it * 4 + 1] = d[1]; v[it * 4 + 2] = d[2]; v[it * 4 + 3] = d[3];
    } else {
      uint2 d = *(const uint2*)(xb + c);
      v[it * 4 + 0] = b2f(d.x & 0xffff); v[it * 4 + 1] = b2f(d.x >> 16);
      v[it * 4 + 2] = b2f(d.y & 0xffff); v[it * 4 + 3] = b2f(d.y >> 16);
    }
  }
  float s = 0.f, s2 = 0.f;
#pragma unroll
  for (int i = 0; i < 12; ++i) { s += v[i]; s2 += v[i] * v[i]; }
#pragma unroll
  for (int off = 32; off >= 1; off >>= 1) {
    s += __shfl_xor(s, off, 64);
    s2 += __shfl_xor(s2, off, 64);
  }
  float inv_n = 1.0f / 768.f;
  float mean = s * inv_n;
  float var = fmaxf(s2 * inv_n - mean * mean, 0.f);
  float rstd = rsqrtf(var + 1e-5f);
  float gate = 0.f;
  if (RES) gate = 1.f / (1.f + __expf(-gatep[0]));
#pragma unroll
  for (int it = 0; it < 3; ++it) {
    int c = (lane + it * 64) * 4;
    float o[4];
#pragma unroll
    for (int i = 0; i < 4; ++i) o[i] = (v[it * 4 + i] - mean) * rstd * g[c + i] + bta[c + i];
    if (RES) {
      const float* rr = resid + (size_t)row * 768 + c;
#pragma unroll
      for (int i = 0; i < 4; ++i) o[i] = rr[i] + gate * o[i];
      *(f32x4*)(outf + (size_t)row * 768 + c) = (f32x4){o[0], o[1], o[2], o[3]};
    }
    uint2 po;
    po.x = (uint32_t)f2b(o[0]) | ((uint32_t)f2b(o[1]) << 16);
    po.y = (uint32_t)f2b(o[2]) | ((uint32_t)f2b(o[3]) << 16);
    *(uint2*)(outb + (size_t)row * 768 + c) = po;
  }
}

// ---------------- MFMA GEMM: C = A(MxK)*BT(NxK)^T ----------------
// BM=64 fixed, BK=64, BN=128. Double-buffered swizzled LDS, 2-deep register
// prefetch, ONE barrier per K-step.
// EPI: 0 none | 1 +bias | 2 +bias,gelu | 3 +bias+resid_f32 | 4 kv-fold (fused LN stats on A)
template <bool AF32, bool BF32, int EPI, bool OUTF32>
__global__ __launch_bounds__(256) void gemm_bt(const void* __restrict__ Av, const void* __restrict__ Bv,
                                               const float* __restrict__ bias,
                                               const float* __restrict__ residf,
                                               const float* __restrict__ ucol,
                                               const float* __restrict__ wcol,
                                               void* __restrict__ Cv, int M, int N, int K) {
  // swizzled layout: elem(row,k) -> u16 off row*64 + (((k>>3) ^ (row&7))<<3) + (k&7)
  __shared__ __align__(16) u16 aT[2][64 * 64];
  __shared__ __align__(16) u16 bT[2][128 * 64];
  __shared__ float rstd_s[EPI == 4 ? 64 : 1];
  __shared__ float mrstd_s[EPI == 4 ? 64 : 1];
  int t = threadIdx.x, lane = t & 63, wave = t >> 6;
  int quad = lane >> 4, lcol = lane & 15;
  int wm = (wave >> 1) * 32, wn = (wave & 1) * 64;
  int ar = t >> 2, ac = (t & 3) * 16;  // A: row ar, cols ac..ac+15 (2 chunks)
  int br = t >> 1, bc = (t & 1) * 32;  // B: row br, cols bc..bc+31 (4 chunks)
  const u16* Ab = (const u16*)Av;
  const float* Af = (const float*)Av;
  const u16* Bb = (const u16*)Bv;
  const float* Bf = (const float*)Bv;
  const size_t arow = (size_t)blockIdx.x * 64 + ar;
  const size_t brow = (size_t)blockIdx.y * 128 + br;
  // swizzled LDS write offsets (u16 units)
  const int aw0 = ar * 64 + (((2 * (t & 3) + 0) ^ (ar & 7)) << 3);
  const int aw1 = ar * 64 + (((2 * (t & 3) + 1) ^ (ar & 7)) << 3);
  const int bw0 = br * 64 + ((((t & 1) * 4 + 0) ^ (br & 7)) << 3);
  const int bw1 = br * 64 + ((((t & 1) * 4 + 1) ^ (br & 7)) << 3);
  const int bw2 = br * 64 + ((((t & 1) * 4 + 2) ^ (br & 7)) << 3);
  const int bw3 = br * 64 + ((((t & 1) * 4 + 3) ^ (br & 7)) << 3);

  float sa = 0.f, sa2 = 0.f;
  f32x4 acc[2][4];
#pragma unroll
  for (int i = 0; i < 2; ++i)
#pragma unroll
    for (int j = 0; j < 4; ++j) acc[i][j] = (f32x4){0.f, 0.f, 0.f, 0.f};

  uint4 aS0[2], bS0[4], aS1[2], bS1[4];

  auto loadA = [&](uint4* aS, int k0) {
    if (AF32) {
      const f32x4* p = (const f32x4*)&Af[arow * K + k0 + ac];
      f32x4 v0 = p[0], v1 = p[1], v2 = p[2], v3 = p[3];
      if (EPI == 4) {
#pragma unroll
        for (int i = 0; i < 4; ++i) {
          sa += v0[i] + v1[i] + v2[i] + v3[i];
          sa2 += v0[i] * v0[i] + v1[i] * v1[i] + v2[i] * v2[i] + v3[i] * v3[i];
        }
      }
      aS[0] = pack8(v0, v1);
      aS[1] = pack8(v2, v3);
    } else {
      const uint4* p = (const uint4*)&Ab[arow * K + k0 + ac];
      aS[0] = p[0];
      aS[1] = p[1];
    }
  };
  auto loadB = [&](uint4* bS, int k0) {
    if (BF32) {
      const f32x4* p = (const f32x4*)&Bf[brow * K + k0 + bc];
#pragma unroll
      for (int i = 0; i < 4; ++i) bS[i] = pack8(p[2 * i], p[2 * i + 1]);
    } else {
      const uint4* p = (const uint4*)&Bb[brow * K + k0 + bc];
#pragma unroll
      for (int i = 0; i < 4; ++i) bS[i] = p[i];
    }
  };
  auto store = [&](const uint4* aS, const uint4* bS, int buf) {
    *(uint4*)&aT[buf][aw0] = aS[0];
    *(uint4*)&aT[buf][aw1] = aS[1];
    *(uint4*)&bT[buf][bw0] = bS[0];
    *(uint4*)&bT[buf][bw1] = bS[1];
    *(uint4*)&bT[buf][bw2] = bS[2];
    *(uint4*)&bT[buf][bw3] = bS[3];
  };
  auto compute = [&](int buf) {
    bf16x8 af[2][2], bfr[4][2];
#pragma unroll
    for (int mt = 0; mt < 2; ++mt) {
      int r = wm + mt * 16 + lcol;
#pragma unroll
      for (int kk = 0; kk < 2; ++kk)
        af[mt][kk] = *(const bf16x8*)&aT[buf][r * 64 + (((kk * 4 + quad) ^ (r & 7)) << 3)];
    }
#pragma unroll
    for (int nt = 0; nt < 4; ++nt) {
      int r = wn + nt * 16 + lcol;
#pragma unroll
      for (int kk = 0; kk < 2; ++kk)
        bfr[nt][kk] = *(const bf16x8*)&bT[buf][r * 64 + (((kk * 4 + quad) ^ (r & 7)) << 3)];
    }
#pragma unroll
    for (int kk = 0; kk < 2; ++kk)
#pragma unroll
      for (int mt = 0; mt < 2; ++mt)
#pragma unroll
        for (int nt = 0; nt < 4; ++nt)
          acc[mt][nt] = __builtin_amdgcn_mfma_f32_16x16x32_bf16(af[mt][kk], bfr[nt][kk], acc[mt][nt], 0, 0, 0);
  };

  const int nk = K >> 6;
  loadA(aS0, 0);
  loadB(bS0, 0);
  if (nk > 1) { loadA(aS1, 64); loadB(bS1, 64); }
  store(aS0, bS0, 0);
  __syncthreads();
  for (int kt = 0; kt < nk; kt += 2) {
    if (kt + 2 < nk) { loadA(aS0, (kt + 2) << 6); loadB(bS0, (kt + 2) << 6); }
    compute(0);
    if (kt + 1 < nk) store(aS1, bS1, 1);
    __syncthreads();
    if (kt + 1 < nk) {
      if (kt + 3 < nk) { loadA(aS1, (kt + 3) << 6); loadB(bS1, (kt + 3) << 6); }
      compute(1);
      if (kt + 2 < nk) store(aS0, bS0, 0);
      __syncthreads();
    }
  }

  if (EPI == 4) {
    float s = sa, s2 = sa2;
    s += __shfl_xor(s, 1, 64);
    s += __shfl_xor(s, 2, 64);
    s2 += __shfl_xor(s2, 1, 64);
    s2 += __shfl_xor(s2, 2, 64);
    if ((t & 3) == 0) {
      float inv_n = 1.0f / (float)K;
      float mean = s * inv_n;
      float var = fmaxf(s2 * inv_n - mean * mean, 0.f);
      float rstd = rsqrtf(var + 1e-5f);
      rstd_s[ar] = rstd;
      mrstd_s[ar] = mean * rstd;
    }
    __syncthreads();
  }
  u16* Cb = (u16*)Cv;
  float* Cf = (float*)Cv;
#pragma unroll
  for (int mt = 0; mt < 2; ++mt) {
#pragma unroll
    for (int nt = 0; nt < 4; ++nt) {
#pragma unroll
      for (int r = 0; r < 4; ++r) {
        int lrow = wm + mt * 16 + quad * 4 + r;
        int row = blockIdx.x * 64 + lrow;
        int col = blockIdx.y * 128 + wn + nt * 16 + lcol;
        float v = acc[mt][nt][r];
        if (EPI == 1 || EPI == 2 || EPI == 3) v += bias[col];
        if (EPI == 2) v = 0.5f * v * (1.f + erff(v * 0.70710678118f));
        if (EPI == 3) v += residf[(size_t)row * N + col];
        if (EPI == 4) v = rstd_s[lrow] * v - mrstd_s[lrow] * ucol[col] + wcol[col] + bias[col];
        size_t idx = (size_t)row * N + col;
        if (OUTF32) Cf[idx] = v; else Cb[idx] = f2b(v);
      }
    }
  }
}

// ---------------- flash attention, MQA (NKV=1), HD=64, no-max softmax, j-split=2 ----------------
__global__ __launch_bounds__(256) void attn_kernel(const u16* __restrict__ qbuf,
                                                   const u16* __restrict__ kvbuf,
                                                   const u16* __restrict__ VT,
                                                   float* __restrict__ Opart,
                                                   float* __restrict__ lpart) {
  __shared__ __align__(16) u16 k_lds[64 * 72];      // K[j][d]
  __shared__ __align__(16) u16 vt_lds[64 * 72];     // V^T[d][j]
  __shared__ __align__(16) u16 p_lds[4 * 16 * 72];  // per-wave P
  int z = blockIdx.z, b = z >> 1, s = z & 1, h = blockIdx.y;
  int t = threadIdx.x;
  int wave = t >> 6, lane = t & 63, quad = lane >> 4, lcol = lane & 15;
  int i0 = blockIdx.x * 64 + wave * 16;
  const u16* qrow = qbuf + ((size_t)(b * 256 + i0 + lcol) * 768 + h * 64 + quad * 8);
  bf16x8 qf0 = *(const bf16x8*)qrow;
  bf16x8 qf1 = *(const bf16x8*)(qrow + 32);
  float l_r[4] = {0.f, 0.f, 0.f, 0.f};
  f32x4 oacc[4];
#pragma unroll
  for (int nt = 0; nt < 4; ++nt) oacc[nt] = (f32x4){0.f, 0.f, 0.f, 0.f};
  int sr = t >> 2, sc = (t & 3) * 16;
  const u16* kbase = kvbuf + ((size_t)b * 4096) * 128;
  const u16* vtbase = VT + (size_t)b * 64 * 4096;
  u16* pw = &p_lds[wave * 16 * 72];

  for (int jt = 0; jt < 32; ++jt) {
    int j0 = s * 2048 + jt * 64;
    const u16* krow = kbase + (size_t)(j0 + sr) * 128 + sc;
    *(uint4*)&k_lds[sr * 72 + sc] = *(const uint4*)(krow);
    *(uint4*)&k_lds[sr * 72 + sc + 8] = *(const uint4*)(krow + 8);
    const u16* vrow = vtbase + (size_t)sr * 4096 + j0 + sc;
    *(uint4*)&vt_lds[sr * 72 + sc] = *(const uint4*)(vrow);
    *(uint4*)&vt_lds[sr * 72 + sc + 8] = *(const uint4*)(vrow + 8);
    __syncthreads();

    f32x4 sc4[4];
#pragma unroll
    for (int nt = 0; nt < 4; ++nt) sc4[nt] = (f32x4){0.f, 0.f, 0.f, 0.f};
#pragma unroll
    for (int nt = 0; nt < 4; ++nt) {
      bf16x8 kb0 = *(const bf16x8*)&k_lds[(nt * 16 + lcol) * 72 + quad * 8];
      bf16x8 kb1 = *(const bf16x8*)&k_lds[(nt * 16 + lcol) * 72 + 32 + quad * 8];
      sc4[nt] = __builtin_amdgcn_mfma_f32_16x16x32_bf16(qf0, kb0, sc4[nt], 0, 0, 0);
      sc4[nt] = __builtin_amdgcn_mfma_f32_16x16x32_bf16(qf1, kb1, sc4[nt], 0, 0, 0);
    }
#pragma unroll
    for (int r = 0; r < 4; ++r) {
      float rsum = 0.f;
#pragma unroll
      for (int nt = 0; nt < 4; ++nt) {
        float p = __expf(sc4[nt][r] * 0.125f);
        sc4[nt][r] = p;
        rsum += p;
      }
      rsum += __shfl_xor(rsum, 1, 64);
      rsum += __shfl_xor(rsum, 2, 64);
      rsum += __shfl_xor(rsum, 4, 64);
      rsum += __shfl_xor(rsum, 8, 64);
      l_r[r] += rsum;
#pragma unroll
      for (int nt = 0; nt < 4; ++nt) pw[(quad * 4 + r) * 72 + nt * 16 + lcol] = f2b(sc4[nt][r]);
    }
#pragma unroll
    for (int ks = 0; ks < 2; ++ks) {
      bf16x8 pa = *(const bf16x8*)&pw[lcol * 72 + ks * 32 + quad * 8];
#pragma unroll
      for (int nt = 0; nt < 4; ++nt) {
        bf16x8 vb = *(const bf16x8*)&vt_lds[(nt * 16 + lcol) * 72 + ks * 32 + quad * 8];
        oacc[nt] = __builtin_amdgcn_mfma_f32_16x16x32_bf16(pa, vb, oacc[nt], 0, 0, 0);
      }
    }
    __syncthreads();
  }
  size_t base = ((size_t)z * 12 + h) * 256;
#pragma unroll
  for (int r = 0; r < 4; ++r) {
    int row = blockIdx.x * 64 + wave * 16 + quad * 4 + r;
#pragma unroll
    for (int nt = 0; nt < 4; ++nt)
      Opart[(base + row) * 64 + nt * 16 + lcol] = oacc[nt][r];
    if (lcol == 0) lpart[base + row] = l_r[r];
  }
}

// ---------------- merge j-split partials -> attn_o bf16 ----------------
__global__ __launch_bounds__(256) void attn_merge(const float* __restrict__ Opart,
                                                  const float* __restrict__ lpart,
                                                  u16* __restrict__ attn_o) {
  int row = blockIdx.x;                      // 0..2047
  int col = blockIdx.y * 256 + threadIdx.x;  // 0..767
  int b = row >> 8, i = row & 255, h = col >> 6, d = col & 63;
  size_t i0 = (((size_t)(b * 2 + 0) * 12 + h) * 256 + i);
  size_t i1 = (((size_t)(b * 2 + 1) * 12 + h) * 256 + i);
  float o = Opart[i0 * 64 + d] + Opart[i1 * 64 + d];
  float l = lpart[i0] + lpart[i1];
  attn_o[(size_t)row * 768 + col] = f2b(o / l);
}

// ---------------- launch ----------------
extern "C" void kernel_launch(void* const* d_in, const int* in_sizes, int n_in, void* d_out,
                              int out_size, void* d_ws, size_t ws_size, hipStream_t stream) {
  (void)in_sizes; (void)n_in; (void)out_size; (void)ws_size;
  const float* hs = (const float*)d_in[0];
  const float* imgf = (const float*)d_in[1];
  const float* ln_img_g = (const float*)d_in[2];
  const float* ln_img_b = (const float*)d_in[3];
  const float* W_bottle = (const float*)d_in[4];
  const float* ln_h_g = (const float*)d_in[5];
  const float* ln_h_b = (const float*)d_in[6];
  const float* Wq = (const float*)d_in[7];
  const float* bq = (const float*)d_in[8];
  const float* Wkv = (const float*)d_in[9];
  const float* bkv = (const float*)d_in[10];
  const float* Wo = (const float*)d_in[11];
  const float* bo = (const float*)d_in[12];
  const float* ln_ao_g = (const float*)d_in[13];
  const float* ln_ao_b = (const float*)d_in[14];
  const float* gatep = (const float*)d_in[15];
  const float* ln_f_g = (const float*)d_in[16];
  const float* ln_f_b = (const float*)d_in[17];
  const float* W1 = (const float*)d_in[18];
  const float* b1 = (const float*)d_in[19];
  const float* W2 = (const float*)d_in[20];
  const float* b2 = (const float*)d_in[21];

  char* sc = (char*)d_ws;
  auto alloc = [&](size_t bytes) {
    char* p = sc;
    sc += (bytes + 63) & ~(size_t)63;
    return p;
  };
  u16* WTq = (u16*)alloc(768 * 768 * 2);
  u16* WTo = (u16*)alloc(768 * 768 * 2);
  u16* WT1 = (u16*)alloc(3072 * 768 * 2);
  u16* WT2 = (u16*)alloc(768 * 3072 * 2);
  u16* WkvT = (u16*)alloc(128 * 768 * 2);
  u16* WcT = (u16*)alloc(128 * 1024 * 2);
  u16* WgT = (u16*)alloc(128 * 1024 * 2);
  float* ucol = (float*)alloc(128 * 4);
  float* wcol = (float*)alloc(128 * 4);
  u16* kvb = (u16*)alloc((size_t)32768 * 128 * 2);
  u16* VT = (u16*)alloc((size_t)8 * 64 * 4096 * 2);
  u16* qin = (u16*)alloc(2048 * 768 * 2);
  u16* qb = (u16*)alloc(2048 * 768 * 2);
  u16* attn_o = (u16*)alloc(2048 * 768 * 2);
  u16* ao = (u16*)alloc(2048 * 768 * 2);
  u16* hbuf = (u16*)alloc(2048 * 768 * 2);
  float* hf32 = (float*)alloc(2048 * 768 * 4);
  u16* ffin = (u16*)alloc(2048 * 768 * 2);
  u16* actb = (u16*)alloc((size_t)2048 * 3072 * 2);
  float* Opart = (float*)alloc((size_t)16 * 12 * 256 * 64 * 4);
  float* lpart = (float*)alloc((size_t)16 * 12 * 256 * 4);

  // weight transposes (f32 -> bf16, (N,K) layout)
  transpose_f2b<<<dim3(24, 24), 256, 0, stream>>>(Wq, WTq, 768, 768);
  transpose_f2b<<<dim3(24, 24), 256, 0, stream>>>(Wo, WTo, 768, 768);
  transpose_f2b<<<dim3(96, 24), 256, 0, stream>>>(W1, WT1, 768, 3072);
  transpose_f2b<<<dim3(24, 96), 256, 0, stream>>>(W2, WT2, 3072, 768);
  transpose_f2b<<<dim3(4, 24), 256, 0, stream>>>(Wkv, WkvT, 768, 128);

  // WcT[n,k] = sum_j WkvT[n,j] * W_bottle[k,j]   (B is f32)
  gemm_bt<false, true, 0, false><<<dim3(2, 8), 256, 0, stream>>>(
      WkvT, W_bottle, nullptr, nullptr, nullptr, nullptr, WcT, 128, 1024, 768);
  prep_wg<<<32, 256, 0, stream>>>(WcT, ln_img_g, ln_img_b, WgT, ucol, wcol);
  // kv = rstd*(x@Wg) - mrstd*u + w + bkv  (A f32, fused LN stats)
  gemm_bt<true, false, 4, false><<<dim3(512, 1), 256, 0, stream>>>(
      imgf, WgT, bkv, nullptr, ucol, wcol, kvb, 32768, 128, 1024);
  // V^T per batch
  vt_kernel<<<dim3(128, 2, 8), 256, 0, stream>>>(kvb, VT);
  // q path
  row_ln<true, false><<<512, 256, 0, stream>>>(hs, ln_h_g, ln_h_b, qin, nullptr, nullptr, nullptr);
  gemm_bt<false, false, 1, false><<<dim3(32, 6), 256, 0, stream>>>(
      qin, WTq, bq, nullptr, nullptr, nullptr, qb, 2048, 768, 768);
  // attention (j-split=2) + merge
  attn_kernel<<<dim3(4, 12, 16), 256, 0, stream>>>(qb, kvb, VT, Opart, lpart);
  attn_merge<<<dim3(2048, 3), 256, 0, stream>>>(Opart, lpart, attn_o);
  // out proj
  gemm_bt<false, false, 1, false><<<dim3(32, 6), 256, 0, stream>>>(
      attn_o, WTo, bo, nullptr, nullptr, nullptr, ao, 2048, 768, 768);
  // h = hs + sigmoid(gate)*LN(ao)  (dual bf16 + f32)
  row_ln<false, true><<<512, 256, 0, stream>>>(ao, ln_ao_g, ln_ao_b, hbuf, hf32, hs, gatep);
  // ffn_in = LN(h)  (from f32 h)
  row_ln<true, false><<<512, 256, 0, stream>>>(hf32, ln_f_g, ln_f_b, ffin, nullptr, nullptr, nullptr);
  // act = gelu(ffn_in @ W1 + b1)
  gemm_bt<false, false, 2, false><<<dim3(32, 24), 256, 0, stream>>>(
      ffin, WT1, b1, nullptr, nullptr, nullptr, actb, 2048, 3072, 768);
  // out = h + act @ W2 + b2  (f32 out)
  gemm_bt<false, false, 3, true><<<dim3(32, 6), 256, 0, stream>>>(
      actb, WT2, b2, hf32, nullptr, nullptr, d_out, 2048, 768, 3072);
}

// Round 2
// 657.030 us; speedup vs baseline: 1.0091x; 1.0091x over previous
//
#include <hip/hip_runtime.h>
#include <cstdint>

typedef unsigned short u16;
typedef __bf16 bf16_t;
typedef bf16_t bf16x8 __attribute__((ext_vector_type(8)));
typedef float f32x4 __attribute__((ext_vector_type(4)));

__device__ __forceinline__ float b2f(u16 v) {
  union { uint32_t u; float f; } c; c.u = ((uint32_t)v) << 16; return c.f;
}
__device__ __forceinline__ u16 f2b(float f) {
  union { float f; uint32_t u; } c; c.f = f;
  uint32_t lsb = (c.u >> 16) & 1u;
  return (u16)((c.u + 0x7fffu + lsb) >> 16);
}
__device__ __forceinline__ uint4 pack8(f32x4 a, f32x4 b) {
  union { uint4 v; u16 s[8]; } r;
  r.s[0] = f2b(a[0]); r.s[1] = f2b(a[1]); r.s[2] = f2b(a[2]); r.s[3] = f2b(a[3]);
  r.s[4] = f2b(b[0]); r.s[5] = f2b(b[1]); r.s[6] = f2b(b[2]); r.s[7] = f2b(b[3]);
  return r.v;
}
// raw barrier: no vmcnt drain (the __syncthreads() drain was the round-1 killer)
__device__ __forceinline__ void phase_barrier() {
  asm volatile("s_waitcnt lgkmcnt(0)" ::: "memory");
  __builtin_amdgcn_s_barrier();
  asm volatile("" ::: "memory");
}

// ---------------- transpose f32 (R,C) -> bf16 (C,R) ----------------
__global__ __launch_bounds__(256) void transpose_f2b(const float* __restrict__ in,
                                                     u16* __restrict__ out, int R, int C) {
  __shared__ __align__(16) u16 tile[32][33];
  int tx = threadIdx.x & 31, ty = threadIdx.x >> 5;
  int c0 = blockIdx.x * 32, r0 = blockIdx.y * 32;
#pragma unroll
  for (int i = 0; i < 4; ++i) {
    int r = r0 + ty + i * 8, c = c0 + tx;
    if (r < R && c < C) tile[ty + i * 8][tx] = f2b(in[(size_t)r * C + c]);
  }
  __syncthreads();
#pragma unroll
  for (int i = 0; i < 4; ++i) {
    int oc = c0 + ty + i * 8, orr = r0 + tx;
    if (oc < C && orr < R) out[(size_t)oc * R + orr] = tile[tx][ty + i * 8];
  }
}

// ---------------- VT[b][d][j] from kvb[b][j][64+d] (bf16) ----------------
__global__ __launch_bounds__(256) void vt_kernel(const u16* __restrict__ kvb, u16* __restrict__ VT) {
  __shared__ __align__(16) u16 tile[32][33];
  int tx = threadIdx.x & 31, ty = threadIdx.x >> 5;
  int j0 = blockIdx.x * 32, d0 = blockIdx.y * 32, b = blockIdx.z;
#pragma unroll
  for (int i = 0; i < 4; ++i) {
    int j = j0 + ty + i * 8, d = d0 + tx;
    tile[ty + i * 8][tx] = kvb[((size_t)b * 4096 + j) * 128 + 64 + d];
  }
  __syncthreads();
#pragma unroll
  for (int i = 0; i < 4; ++i) {
    int d = d0 + ty + i * 8, j = j0 + tx;
    VT[((size_t)b * 64 + d) * 4096 + j] = tile[tx][ty + i * 8];
  }
}

// ---------------- WgT[n,k]=g[k]*WcT[n,k]; u[n]=sum g*Wc; w[n]=sum b*Wc ----------------
__global__ __launch_bounds__(256) void prep_wg(const u16* __restrict__ WcT, const float* __restrict__ g,
                                               const float* __restrict__ b, u16* __restrict__ WgT,
                                               float* __restrict__ ucol, float* __restrict__ wcol) {
  int n = blockIdx.x * 4 + (threadIdx.x >> 6);
  int lane = threadIdx.x & 63;
  const u16* src = WcT + (size_t)n * 1024;
  u16* dst = WgT + (size_t)n * 1024;
  float su = 0.f, sw = 0.f;
  for (int k = lane; k < 1024; k += 64) {
    float wc = b2f(src[k]);
    float wg = g[k] * wc;
    dst[k] = f2b(wg);
    su += wg;
    sw += b[k] * wc;
  }
#pragma unroll
  for (int off = 32; off >= 1; off >>= 1) {
    su += __shfl_xor(su, off, 64);
    sw += __shfl_xor(sw, off, 64);
  }
  if (lane == 0) { ucol[n] = su; wcol[n] = sw; }
}

// ---------------- row layernorm (ncols=768): 1 wave/row ----------------
template <bool XF32, bool RES>
__global__ __launch_bounds__(256) void row_ln(const void* __restrict__ xv, const float* __restrict__ g,
                                              const float* __restrict__ bta, u16* __restrict__ outb,
                                              float* __restrict__ outf,
                                              const float* __restrict__ resid,
                                              const float* __restrict__ gatep) {
  int row = blockIdx.x * 4 + (threadIdx.x >> 6);
  int lane = threadIdx.x & 63;
  const u16* xb = (const u16*)xv + (size_t)row * 768;
  const float* xf = (const float*)xv + (size_t)row * 768;
  float v[12];
#pragma unroll
  for (int it = 0; it < 3; ++it) {
    int c = (lane + it * 64) * 4;
    if (XF32) {
      f32x4 d = *(const f32x4*)(xf + c);
      v[it * 4 + 0] = d[0]; v[it * 4 + 1] = d[1]; v[it * 4 + 2] = d[2]; v[it * 4 + 3] = d[3];
    } else {
      uint2 d = *(const uint2*)(xb + c);
      v[it * 4 + 0] = b2f(d.x & 0xffff); v[it * 4 + 1] = b2f(d.x >> 16);
      v[it * 4 + 2] = b2f(d.y & 0xffff); v[it * 4 + 3] = b2f(d.y >> 16);
    }
  }
  float s = 0.f, s2 = 0.f;
#pragma unroll
  for (int i = 0; i < 12; ++i) { s += v[i]; s2 += v[i] * v[i]; }
#pragma unroll
  for (int off = 32; off >= 1; off >>= 1) {
    s += __shfl_xor(s, off, 64);
    s2 += __shfl_xor(s2, off, 64);
  }
  float inv_n = 1.0f / 768.f;
  float mean = s * inv_n;
  float var = fmaxf(s2 * inv_n - mean * mean, 0.f);
  float rstd = rsqrtf(var + 1e-5f);
  float gate = 0.f;
  if (RES) gate = 1.f / (1.f + __expf(-gatep[0]));
#pragma unroll
  for (int it = 0; it < 3; ++it) {
    int c = (lane + it * 64) * 4;
    float o[4];
#pragma unroll
    for (int i = 0; i < 4; ++i) o[i] = (v[it * 4 + i] - mean) * rstd * g[c + i] + bta[c + i];
    if (RES) {
      const float* rr = resid + (size_t)row * 768 + c;
#pragma unroll
      for (int i = 0; i < 4; ++i) o[i] = rr[i] + gate * o[i];
      *(f32x4*)(outf + (size_t)row * 768 + c) = (f32x4){o[0], o[1], o[2], o[3]};
    }
    uint2 po;
    po.x = (uint32_t)f2b(o[0]) | ((uint32_t)f2b(o[1]) << 16);
    po.y = (uint32_t)f2b(o[2]) | ((uint32_t)f2b(o[3]) << 16);
    *(uint2*)(outb + (size_t)row * 768 + c) = po;
  }
}

// ---------------- MFMA GEMM: C = A(MxK)*BT(NxK)^T ----------------
// BM=64, BK=64, BN in {64,128}. Double-buffered swizzled LDS, issue-early/
// write-late reg staging (T14), raw s_barrier (no vmcnt drain), 1 barrier/K-step.
// EPI: 0 none | 1 +bias | 2 +bias,gelu | 3 +bias+resid_f32 | 4 kv-fold (fused LN stats on A)
template <int BN, bool AF32, bool BF32, int EPI, bool OUTF32>
__global__ __launch_bounds__(256) void gemm_bt(const void* __restrict__ Av, const void* __restrict__ Bv,
                                               const float* __restrict__ bias,
                                               const float* __restrict__ residf,
                                               const float* __restrict__ ucol,
                                               const float* __restrict__ wcol,
                                               void* __restrict__ Cv, int M, int N, int K) {
  constexpr int WN = BN / 64;      // waves along N (1 or 2)
  constexpr int WM = 4 / WN;       // waves along M
  constexpr int MT = 64 / (16 * WM);  // m-tiles per wave (1 or 2)
  constexpr int TPR = 256 / BN;    // threads per B row (2 or 4)
  constexpr int CB = 8 / TPR;      // B uint4 chunks per thread (4 or 2)
  // swizzled layout: elem(row,k) -> u16 off row*64 + (((k>>3) ^ (row&7))<<3) + (k&7)
  __shared__ __align__(16) u16 aT[2][64 * 64];
  __shared__ __align__(16) u16 bT[2][BN * 64];
  __shared__ float rstd_s[EPI == 4 ? 64 : 1];
  __shared__ float mrstd_s[EPI == 4 ? 64 : 1];
  int t = threadIdx.x, lane = t & 63, wave = t >> 6;
  int quad = lane >> 4, lcol = lane & 15;
  int wm = (wave / WN) * (16 * MT), wn = (wave % WN) * 64;
  int ar = t >> 2, ac = (t & 3) * 16;       // A: row ar, 16 elems (2 chunks)
  int br = t / TPR, bc = (t % TPR) * (64 / TPR);  // B: row br, CB chunks
  const u16* Ab = (const u16*)Av;
  const float* Af = (const float*)Av;
  const u16* Bb = (const u16*)Bv;
  const float* Bf = (const float*)Bv;
  const size_t arow = (size_t)blockIdx.x * 64 + ar;
  const size_t brow = (size_t)blockIdx.y * BN + br;
  // swizzled LDS write offsets (u16 units)
  int aw[2], bw[CB];
#pragma unroll
  for (int j = 0; j < 2; ++j) aw[j] = ar * 64 + (((2 * (t & 3) + j) ^ (ar & 7)) << 3);
#pragma unroll
  for (int j = 0; j < CB; ++j) bw[j] = br * 64 + ((((t % TPR) * CB + j) ^ (br & 7)) << 3);

  float sa = 0.f, sa2 = 0.f;
  f32x4 acc[MT][4];
#pragma unroll
  for (int i = 0; i < MT; ++i)
#pragma unroll
    for (int j = 0; j < 4; ++j) acc[i][j] = (f32x4){0.f, 0.f, 0.f, 0.f};

  // staging registers (raw until store; pack/stats deferred to store site)
  f32x4 araw[4]; uint4 aS[2];
  f32x4 braw[2 * CB]; uint4 bS[CB];

  auto loadA = [&](int k0) {
    if (AF32) {
      const f32x4* p = (const f32x4*)&Af[arow * K + k0 + ac];
#pragma unroll
      for (int i = 0; i < 4; ++i) araw[i] = p[i];
    } else {
      const uint4* p = (const uint4*)&Ab[arow * K + k0 + ac];
      aS[0] = p[0]; aS[1] = p[1];
    }
  };
  auto loadB = [&](int k0) {
    if (BF32) {
      const f32x4* p = (const f32x4*)&Bf[brow * K + k0 + bc];
#pragma unroll
      for (int i = 0; i < 2 * CB; ++i) braw[i] = p[i];
    } else {
      const uint4* p = (const uint4*)&Bb[brow * K + k0 + bc];
#pragma unroll
      for (int i = 0; i < CB; ++i) bS[i] = p[i];
    }
  };
  auto storeAB = [&](int buf) {
    if (AF32) {
      if (EPI == 4) {
#pragma unroll
        for (int i = 0; i < 4; ++i)
#pragma unroll
          for (int j = 0; j < 4; ++j) { sa += araw[i][j]; sa2 += araw[i][j] * araw[i][j]; }
      }
      aS[0] = pack8(araw[0], araw[1]);
      aS[1] = pack8(araw[2], araw[3]);
    }
    if (BF32) {
#pragma unroll
      for (int i = 0; i < CB; ++i) bS[i] = pack8(braw[2 * i], braw[2 * i + 1]);
    }
    *(uint4*)&aT[buf][aw[0]] = aS[0];
    *(uint4*)&aT[buf][aw[1]] = aS[1];
#pragma unroll
    for (int i = 0; i < CB; ++i) *(uint4*)&bT[buf][bw[i]] = bS[i];
  };
  auto compute = [&](int buf) {
    bf16x8 af[MT][2], bfr[4][2];
#pragma unroll
    for (int mt = 0; mt < MT; ++mt) {
      int r = wm + mt * 16 + lcol;
#pragma unroll
      for (int kk = 0; kk < 2; ++kk)
        af[mt][kk] = *(const bf16x8*)&aT[buf][r * 64 + (((kk * 4 + quad) ^ (r & 7)) << 3)];
    }
#pragma unroll
    for (int nt = 0; nt < 4; ++nt) {
      int r = wn + nt * 16 + lcol;
#pragma unroll
      for (int kk = 0; kk < 2; ++kk)
        bfr[nt][kk] = *(const bf16x8*)&bT[buf][r * 64 + (((kk * 4 + quad) ^ (r & 7)) << 3)];
    }
#pragma unroll
    for (int kk = 0; kk < 2; ++kk)
#pragma unroll
      for (int mt = 0; mt < MT; ++mt)
#pragma unroll
        for (int nt = 0; nt < 4; ++nt)
          acc[mt][nt] = __builtin_amdgcn_mfma_f32_16x16x32_bf16(af[mt][kk], bfr[nt][kk], acc[mt][nt], 0, 0, 0);
  };

  const int nk = K >> 6;
  // prologue: stage tile 0 (eager; one-time latency)
  loadA(0); loadB(0);
  storeAB(0);
  phase_barrier();
  int cur = 0;
  for (int kt = 0; kt < nk; ++kt) {
    if (kt + 1 < nk) { loadA((kt + 1) << 6); loadB((kt + 1) << 6); }  // issue early
    compute(cur);                                                     // hide latency
    if (kt + 1 < nk) storeAB(cur ^ 1);                                // write late
    phase_barrier();
    cur ^= 1;
  }

  if (EPI == 4) {
    float s = sa, s2 = sa2;
    s += __shfl_xor(s, 1, 64);
    s += __shfl_xor(s, 2, 64);
    s2 += __shfl_xor(s2, 1, 64);
    s2 += __shfl_xor(s2, 2, 64);
    if ((t & 3) == 0) {
      float inv_n = 1.0f / (float)K;
      float mean = s * inv_n;
      float var = fmaxf(s2 * inv_n - mean * mean, 0.f);
      float rstd = rsqrtf(var + 1e-5f);
      rstd_s[ar] = rstd;
      mrstd_s[ar] = mean * rstd;
    }
    __syncthreads();
  }
  u16* Cb = (u16*)Cv;
  float* Cf = (float*)Cv;
#pragma unroll
  for (int mt = 0; mt < MT; ++mt) {
#pragma unroll
    for (int nt = 0; nt < 4; ++nt) {
#pragma unroll
      for (int r = 0; r < 4; ++r) {
        int lrow = wm + mt * 16 + quad * 4 + r;
        int row = blockIdx.x * 64 + lrow;
        int col = blockIdx.y * BN + wn + nt * 16 + lcol;
        float v = acc[mt][nt][r];
        if (EPI == 1 || EPI == 2 || EPI == 3) v += bias[col];
        if (EPI == 2) v = 0.5f * v * (1.f + erff(v * 0.70710678118f));
        if (EPI == 3) v += residf[(size_t)row * N + col];
        if (EPI == 4) v = rstd_s[lrow] * v - mrstd_s[lrow] * ucol[col] + wcol[col] + bias[col];
        size_t idx = (size_t)row * N + col;
        if (OUTF32) Cf[idx] = v; else Cb[idx] = f2b(v);
      }
    }
  }
}

// ---------------- flash attention, MQA (NKV=1), HD=64, no-max softmax, j-split=2 ----------------
__global__ __launch_bounds__(256) void attn_kernel(const u16* __restrict__ qbuf,
                                                   const u16* __restrict__ kvbuf,
                                                   const u16* __restrict__ VT,
                                                   float* __restrict__ Opart,
                                                   float* __restrict__ lpart) {
  __shared__ __align__(16) u16 k_lds[64 * 72];      // K[j][d]
  __shared__ __align__(16) u16 vt_lds[64 * 72];     // V^T[d][j]
  __shared__ __align__(16) u16 p_lds[4 * 16 * 72];  // per-wave P
  int z = blockIdx.z, b = z >> 1, s = z & 1, h = blockIdx.y;
  int t = threadIdx.x;
  int wave = t >> 6, lane = t & 63, quad = lane >> 4, lcol = lane & 15;
  int i0 = blockIdx.x * 64 + wave * 16;
  const u16* qrow = qbuf + ((size_t)(b * 256 + i0 + lcol) * 768 + h * 64 + quad * 8);
  bf16x8 qf0 = *(const bf16x8*)qrow;
  bf16x8 qf1 = *(const bf16x8*)(qrow + 32);
  float l_r[4] = {0.f, 0.f, 0.f, 0.f};
  f32x4 oacc[4];
#pragma unroll
  for (int nt = 0; nt < 4; ++nt) oacc[nt] = (f32x4){0.f, 0.f, 0.f, 0.f};
  int sr = t >> 2, sc = (t & 3) * 16;
  const u16* kbase = kvbuf + ((size_t)b * 4096) * 128;
  const u16* vtbase = VT + (size_t)b * 64 * 4096;
  u16* pw = &p_lds[wave * 16 * 72];

  for (int jt = 0; jt < 32; ++jt) {
    int j0 = s * 2048 + jt * 64;
    const u16* krow = kbase + (size_t)(j0 + sr) * 128 + sc;
    *(uint4*)&k_lds[sr * 72 + sc] = *(const uint4*)(krow);
    *(uint4*)&k_lds[sr * 72 + sc + 8] = *(const uint4*)(krow + 8);
    const u16* vrow = vtbase + (size_t)sr * 4096 + j0 + sc;
    *(uint4*)&vt_lds[sr * 72 + sc] = *(const uint4*)(vrow);
    *(uint4*)&vt_lds[sr * 72 + sc + 8] = *(const uint4*)(vrow + 8);
    __syncthreads();

    f32x4 sc4[4];
#pragma unroll
    for (int nt = 0; nt < 4; ++nt) sc4[nt] = (f32x4){0.f, 0.f, 0.f, 0.f};
#pragma unroll
    for (int nt = 0; nt < 4; ++nt) {
      bf16x8 kb0 = *(const bf16x8*)&k_lds[(nt * 16 + lcol) * 72 + quad * 8];
      bf16x8 kb1 = *(const bf16x8*)&k_lds[(nt * 16 + lcol) * 72 + 32 + quad * 8];
      sc4[nt] = __builtin_amdgcn_mfma_f32_16x16x32_bf16(qf0, kb0, sc4[nt], 0, 0, 0);
      sc4[nt] = __builtin_amdgcn_mfma_f32_16x16x32_bf16(qf1, kb1, sc4[nt], 0, 0, 0);
    }
#pragma unroll
    for (int r = 0; r < 4; ++r) {
      float rsum = 0.f;
#pragma unroll
      for (int nt = 0; nt < 4; ++nt) {
        float p = __expf(sc4[nt][r] * 0.125f);
        sc4[nt][r] = p;
        rsum += p;
      }
      rsum += __shfl_xor(rsum, 1, 64);
      rsum += __shfl_xor(rsum, 2, 64);
      rsum += __shfl_xor(rsum, 4, 64);
      rsum += __shfl_xor(rsum, 8, 64);
      l_r[r] += rsum;
#pragma unroll
      for (int nt = 0; nt < 4; ++nt) pw[(quad * 4 + r) * 72 + nt * 16 + lcol] = f2b(sc4[nt][r]);
    }
#pragma unroll
    for (int ks = 0; ks < 2; ++ks) {
      bf16x8 pa = *(const bf16x8*)&pw[lcol * 72 + ks * 32 + quad * 8];
#pragma unroll
      for (int nt = 0; nt < 4; ++nt) {
        bf16x8 vb = *(const bf16x8*)&vt_lds[(nt * 16 + lcol) * 72 + ks * 32 + quad * 8];
        oacc[nt] = __builtin_amdgcn_mfma_f32_16x16x32_bf16(pa, vb, oacc[nt], 0, 0, 0);
      }
    }
    __syncthreads();
  }
  size_t base = ((size_t)z * 12 + h) * 256;
#pragma unroll
  for (int r = 0; r < 4; ++r) {
    int row = blockIdx.x * 64 + wave * 16 + quad * 4 + r;
#pragma unroll
    for (int nt = 0; nt < 4; ++nt)
      Opart[(base + row) * 64 + nt * 16 + lcol] = oacc[nt][r];
    if (lcol == 0) lpart[base + row] = l_r[r];
  }
}

// ---------------- merge j-split partials -> attn_o bf16 ----------------
__global__ __launch_bounds__(256) void attn_merge(const float* __restrict__ Opart,
                                                  const float* __restrict__ lpart,
                                                  u16* __restrict__ attn_o) {
  int row = blockIdx.x;                      // 0..2047
  int col = blockIdx.y * 256 + threadIdx.x;  // 0..767
  int b = row >> 8, i = row & 255, h = col >> 6, d = col & 63;
  size_t i0 = (((size_t)(b * 2 + 0) * 12 + h) * 256 + i);
  size_t i1 = (((size_t)(b * 2 + 1) * 12 + h) * 256 + i);
  float o = Opart[i0 * 64 + d] + Opart[i1 * 64 + d];
  float l = lpart[i0] + lpart[i1];
  attn_o[(size_t)row * 768 + col] = f2b(o / l);
}

// ---------------- launch ----------------
extern "C" void kernel_launch(void* const* d_in, const int* in_sizes, int n_in, void* d_out,
                              int out_size, void* d_ws, size_t ws_size, hipStream_t stream) {
  (void)in_sizes; (void)n_in; (void)out_size; (void)ws_size;
  const float* hs = (const float*)d_in[0];
  const float* imgf = (const float*)d_in[1];
  const float* ln_img_g = (const float*)d_in[2];
  const float* ln_img_b = (const float*)d_in[3];
  const float* W_bottle = (const float*)d_in[4];
  const float* ln_h_g = (const float*)d_in[5];
  const float* ln_h_b = (const float*)d_in[6];
  const float* Wq = (const float*)d_in[7];
  const float* bq = (const float*)d_in[8];
  const float* Wkv = (const float*)d_in[9];
  const float* bkv = (const float*)d_in[10];
  const float* Wo = (const float*)d_in[11];
  const float* bo = (const float*)d_in[12];
  const float* ln_ao_g = (const float*)d_in[13];
  const float* ln_ao_b = (const float*)d_in[14];
  const float* gatep = (const float*)d_in[15];
  const float* ln_f_g = (const float*)d_in[16];
  const float* ln_f_b = (const float*)d_in[17];
  const float* W1 = (const float*)d_in[18];
  const float* b1 = (const float*)d_in[19];
  const float* W2 = (const float*)d_in[20];
  const float* b2 = (const float*)d_in[21];

  char* sc = (char*)d_ws;
  auto alloc = [&](size_t bytes) {
    char* p = sc;
    sc += (bytes + 63) & ~(size_t)63;
    return p;
  };
  u16* WTq = (u16*)alloc(768 * 768 * 2);
  u16* WTo = (u16*)alloc(768 * 768 * 2);
  u16* WT1 = (u16*)alloc(3072 * 768 * 2);
  u16* WT2 = (u16*)alloc(768 * 3072 * 2);
  u16* WkvT = (u16*)alloc(128 * 768 * 2);
  u16* WcT = (u16*)alloc(128 * 1024 * 2);
  u16* WgT = (u16*)alloc(128 * 1024 * 2);
  float* ucol = (float*)alloc(128 * 4);
  float* wcol = (float*)alloc(128 * 4);
  u16* kvb = (u16*)alloc((size_t)32768 * 128 * 2);
  u16* VT = (u16*)alloc((size_t)8 * 64 * 4096 * 2);
  u16* qin = (u16*)alloc(2048 * 768 * 2);
  u16* qb = (u16*)alloc(2048 * 768 * 2);
  u16* attn_o = (u16*)alloc(2048 * 768 * 2);
  u16* ao = (u16*)alloc(2048 * 768 * 2);
  u16* hbuf = (u16*)alloc(2048 * 768 * 2);
  float* hf32 = (float*)alloc(2048 * 768 * 4);
  u16* ffin = (u16*)alloc(2048 * 768 * 2);
  u16* actb = (u16*)alloc((size_t)2048 * 3072 * 2);
  float* Opart = (float*)alloc((size_t)16 * 12 * 256 * 64 * 4);
  float* lpart = (float*)alloc((size_t)16 * 12 * 256 * 4);

  // weight transposes (f32 -> bf16, (N,K) layout)
  transpose_f2b<<<dim3(24, 24), 256, 0, stream>>>(Wq, WTq, 768, 768);
  transpose_f2b<<<dim3(24, 24), 256, 0, stream>>>(Wo, WTo, 768, 768);
  transpose_f2b<<<dim3(96, 24), 256, 0, stream>>>(W1, WT1, 768, 3072);
  transpose_f2b<<<dim3(24, 96), 256, 0, stream>>>(W2, WT2, 3072, 768);
  transpose_f2b<<<dim3(4, 24), 256, 0, stream>>>(Wkv, WkvT, 768, 128);

  // WcT[n,k] = sum_j WkvT[n,j] * W_bottle[k,j]   (B is f32)
  gemm_bt<128, false, true, 0, false><<<dim3(2, 8), 256, 0, stream>>>(
      WkvT, W_bottle, nullptr, nullptr, nullptr, nullptr, WcT, 128, 1024, 768);
  prep_wg<<<32, 256, 0, stream>>>(WcT, ln_img_g, ln_img_b, WgT, ucol, wcol);
  // kv = rstd*(x@Wg) - mrstd*u + w + bkv  (A f32, fused LN stats)
  gemm_bt<128, true, false, 4, false><<<dim3(512, 1), 256, 0, stream>>>(
      imgf, WgT, bkv, nullptr, ucol, wcol, kvb, 32768, 128, 1024);
  // V^T per batch
  vt_kernel<<<dim3(128, 2, 8), 256, 0, stream>>>(kvb, VT);
  // q path
  row_ln<true, false><<<512, 256, 0, stream>>>(hs, ln_h_g, ln_h_b, qin, nullptr, nullptr, nullptr);
  gemm_bt<64, false, false, 1, false><<<dim3(32, 12), 256, 0, stream>>>(
      qin, WTq, bq, nullptr, nullptr, nullptr, qb, 2048, 768, 768);
  // attention (j-split=2) + merge
  attn_kernel<<<dim3(4, 12, 16), 256, 0, stream>>>(qb, kvb, VT, Opart, lpart);
  attn_merge<<<dim3(2048, 3), 256, 0, stream>>>(Opart, lpart, attn_o);
  // out proj
  gemm_bt<64, false, false, 1, false><<<dim3(32, 12), 256, 0, stream>>>(
      attn_o, WTo, bo, nullptr, nullptr, nullptr, ao, 2048, 768, 768);
  // h = hs + sigmoid(gate)*LN(ao)  (dual bf16 + f32)
  row_ln<false, true><<<512, 256, 0, stream>>>(ao, ln_ao_g, ln_ao_b, hbuf, hf32, hs, gatep);
  // ffn_in = LN(h)  (from f32 h)
  row_ln<true, false><<<512, 256, 0, stream>>>(hf32, ln_f_g, ln_f_b, ffin, nullptr, nullptr, nullptr);
  // act = gelu(ffn_in @ W1 + b1)
  gemm_bt<128, false, false, 2, false><<<dim3(32, 24), 256, 0, stream>>>(
      ffin, WT1, b1, nullptr, nullptr, nullptr, actb, 2048, 3072, 768);
  // out = h + act @ W2 + b2  (f32 out)
  gemm_bt<64, false, false, 3, true><<<dim3(32, 12), 256, 0, stream>>>(
      actb, WT2, b2, hf32, nullptr, nullptr, d_out, 2048, 768, 3072);
}

// Round 3
// 636.153 us; speedup vs baseline: 1.0422x; 1.0328x over previous
//
#include <hip/hip_runtime.h>
#include <cstdint>

typedef unsigned short u16;
typedef __bf16 bf16_t;
typedef bf16_t bf16x8 __attribute__((ext_vector_type(8)));
typedef float f32x4 __attribute__((ext_vector_type(4)));

__device__ __forceinline__ float b2f(u16 v) {
  union { uint32_t u; float f; } c; c.u = ((uint32_t)v) << 16; return c.f;
}
__device__ __forceinline__ u16 f2b(float f) {
  union { float f; uint32_t u; } c; c.f = f;
  uint32_t lsb = (c.u >> 16) & 1u;
  return (u16)((c.u + 0x7fffu + lsb) >> 16);
}
__device__ __forceinline__ uint4 pack8(f32x4 a, f32x4 b) {
  union { uint4 v; u16 s[8]; } r;
  r.s[0] = f2b(a[0]); r.s[1] = f2b(a[1]); r.s[2] = f2b(a[2]); r.s[3] = f2b(a[3]);
  r.s[4] = f2b(b[0]); r.s[5] = f2b(b[1]); r.s[6] = f2b(b[2]); r.s[7] = f2b(b[3]);
  return r.v;
}
// raw barrier: no vmcnt drain
__device__ __forceinline__ void phase_barrier() {
  asm volatile("s_waitcnt lgkmcnt(0)" ::: "memory");
  __builtin_amdgcn_s_barrier();
  asm volatile("" ::: "memory");
}
// bijective chunked XCD swizzle (m204): blocks with the same lid%8 land on the
// same XCD (RR dispatch); give each XCD a CONTIGUOUS chunk of work ids so
// same-panel blocks share that XCD's L2.
__device__ __forceinline__ int xcd_swizzle(int lid, int nwg) {
  int q = nwg >> 3, r = nwg & 7, x = lid & 7, s = lid >> 3;
  return (x < r ? x * (q + 1) : r * (q + 1) + (x - r) * q) + s;
}

// ---------------- transpose f32 (R,C) -> bf16 (C,R) ----------------
__global__ __launch_bounds__(256) void transpose_f2b(const float* __restrict__ in,
                                                     u16* __restrict__ out, int R, int C) {
  __shared__ __align__(16) u16 tile[32][33];
  int tx = threadIdx.x & 31, ty = threadIdx.x >> 5;
  int c0 = blockIdx.x * 32, r0 = blockIdx.y * 32;
#pragma unroll
  for (int i = 0; i < 4; ++i) {
    int r = r0 + ty + i * 8, c = c0 + tx;
    if (r < R && c < C) tile[ty + i * 8][tx] = f2b(in[(size_t)r * C + c]);
  }
  __syncthreads();
#pragma unroll
  for (int i = 0; i < 4; ++i) {
    int oc = c0 + ty + i * 8, orr = r0 + tx;
    if (oc < C && orr < R) out[(size_t)oc * R + orr] = tile[tx][ty + i * 8];
  }
}

// ---------------- VT[b][d][j] from kvb[b][j][64+d] (bf16) ----------------
__global__ __launch_bounds__(256) void vt_kernel(const u16* __restrict__ kvb, u16* __restrict__ VT) {
  __shared__ __align__(16) u16 tile[32][33];
  int tx = threadIdx.x & 31, ty = threadIdx.x >> 5;
  int j0 = blockIdx.x * 32, d0 = blockIdx.y * 32, b = blockIdx.z;
#pragma unroll
  for (int i = 0; i < 4; ++i) {
    int j = j0 + ty + i * 8, d = d0 + tx;
    tile[ty + i * 8][tx] = kvb[((size_t)b * 4096 + j) * 128 + 64 + d];
  }
  __syncthreads();
#pragma unroll
  for (int i = 0; i < 4; ++i) {
    int d = d0 + ty + i * 8, j = j0 + tx;
    VT[((size_t)b * 64 + d) * 4096 + j] = tile[tx][ty + i * 8];
  }
}

// ---------------- WgT[n,k]=g[k]*WcT[n,k]; u[n]=sum g*Wc; w[n]=sum b*Wc ----------------
__global__ __launch_bounds__(256) void prep_wg(const u16* __restrict__ WcT, const float* __restrict__ g,
                                               const float* __restrict__ b, u16* __restrict__ WgT,
                                               float* __restrict__ ucol, float* __restrict__ wcol) {
  int n = blockIdx.x * 4 + (threadIdx.x >> 6);
  int lane = threadIdx.x & 63;
  const u16* src = WcT + (size_t)n * 1024;
  u16* dst = WgT + (size_t)n * 1024;
  float su = 0.f, sw = 0.f;
  for (int k = lane; k < 1024; k += 64) {
    float wc = b2f(src[k]);
    float wg = g[k] * wc;
    dst[k] = f2b(wg);
    su += wg;
    sw += b[k] * wc;
  }
#pragma unroll
  for (int off = 32; off >= 1; off >>= 1) {
    su += __shfl_xor(su, off, 64);
    sw += __shfl_xor(sw, off, 64);
  }
  if (lane == 0) { ucol[n] = su; wcol[n] = sw; }
}

// ---------------- row layernorm (ncols=768): 1 wave/row ----------------
template <bool XF32, bool RES>
__global__ __launch_bounds__(256) void row_ln(const void* __restrict__ xv, const float* __restrict__ g,
                                              const float* __restrict__ bta, u16* __restrict__ outb,
                                              float* __restrict__ outf,
                                              const float* __restrict__ resid,
                                              const float* __restrict__ gatep) {
  int row = blockIdx.x * 4 + (threadIdx.x >> 6);
  int lane = threadIdx.x & 63;
  const u16* xb = (const u16*)xv + (size_t)row * 768;
  const float* xf = (const float*)xv + (size_t)row * 768;
  float v[12];
#pragma unroll
  for (int it = 0; it < 3; ++it) {
    int c = (lane + it * 64) * 4;
    if (XF32) {
      f32x4 d = *(const f32x4*)(xf + c);
      v[it * 4 + 0] = d[0]; v[it * 4 + 1] = d[1]; v[it * 4 + 2] = d[2]; v[it * 4 + 3] = d[3];
    } else {
      uint2 d = *(const uint2*)(xb + c);
      v[it * 4 + 0] = b2f(d.x & 0xffff); v[it * 4 + 1] = b2f(d.x >> 16);
      v[it * 4 + 2] = b2f(d.y & 0xffff); v[it * 4 + 3] = b2f(d.y >> 16);
    }
  }
  float s = 0.f, s2 = 0.f;
#pragma unroll
  for (int i = 0; i < 12; ++i) { s += v[i]; s2 += v[i] * v[i]; }
#pragma unroll
  for (int off = 32; off >= 1; off >>= 1) {
    s += __shfl_xor(s, off, 64);
    s2 += __shfl_xor(s2, off, 64);
  }
  float inv_n = 1.0f / 768.f;
  float mean = s * inv_n;
  float var = fmaxf(s2 * inv_n - mean * mean, 0.f);
  float rstd = rsqrtf(var + 1e-5f);
  float gate = 0.f;
  if (RES) gate = 1.f / (1.f + __expf(-gatep[0]));
#pragma unroll
  for (int it = 0; it < 3; ++it) {
    int c = (lane + it * 64) * 4;
    float o[4];
#pragma unroll
    for (int i = 0; i < 4; ++i) o[i] = (v[it * 4 + i] - mean) * rstd * g[c + i] + bta[c + i];
    if (RES) {
      const float* rr = resid + (size_t)row * 768 + c;
#pragma unroll
      for (int i = 0; i < 4; ++i) o[i] = rr[i] + gate * o[i];
      *(f32x4*)(outf + (size_t)row * 768 + c) = (f32x4){o[0], o[1], o[2], o[3]};
    }
    uint2 po;
    po.x = (uint32_t)f2b(o[0]) | ((uint32_t)f2b(o[1]) << 16);
    po.y = (uint32_t)f2b(o[2]) | ((uint32_t)f2b(o[3]) << 16);
    *(uint2*)(outb + (size_t)row * 768 + c) = po;
  }
}

// ---------------- MFMA GEMM: C = A(MxK)*BT(NxK)^T ----------------
// BM=64, BK=64, BN in {64,128}. XCD-chunked swizzle; dbuf swizzled LDS;
// issue-early/write-late reg staging; raw s_barrier; optional split-K.
// EPI: 0 none | 1 +bias | 2 +bias,gelu | 3 +bias+resid_f32 | 4 kv-fold (fused LN stats on A)
template <int BN, int SPLITK, bool AF32, bool BF32, int EPI, bool OUTF32>
__global__ __launch_bounds__(256) void gemm_bt(const void* __restrict__ Av, const void* __restrict__ Bv,
                                               const float* __restrict__ bias,
                                               const float* __restrict__ residf,
                                               const float* __restrict__ ucol,
                                               const float* __restrict__ wcol,
                                               void* __restrict__ Cv, int M, int N, int K) {
  constexpr int WN = BN / 64;
  constexpr int WM = 4 / WN;
  constexpr int MT = 64 / (16 * WM);
  constexpr int TPR = 256 / BN;
  constexpr int CB = 8 / TPR;
  __shared__ __align__(16) u16 aT[2][64 * 64];
  __shared__ __align__(16) u16 bT[2][BN * 64];
  __shared__ float rstd_s[EPI == 4 ? 64 : 1];
  __shared__ float mrstd_s[EPI == 4 ? 64 : 1];
  // XCD-chunked work remap
  int nwg = (int)(gridDim.x * gridDim.y * gridDim.z);
  int lid = ((int)blockIdx.z * (int)gridDim.y + (int)blockIdx.y) * (int)gridDim.x + (int)blockIdx.x;
  int wid = xcd_swizzle(lid, nwg);
  int bx = wid % (int)gridDim.x;
  int byz = wid / (int)gridDim.x;
  int by = byz % (int)gridDim.y;
  int bz = byz / (int)gridDim.y;

  int t = threadIdx.x, lane = t & 63, wave = t >> 6;
  int quad = lane >> 4, lcol = lane & 15;
  int wm = (wave / WN) * (16 * MT), wn = (wave % WN) * 64;
  int ar = t >> 2, ac = (t & 3) * 16;
  int br = t / TPR, bc = (t % TPR) * (64 / TPR);
  const u16* Ab = (const u16*)Av;
  const float* Af = (const float*)Av;
  const u16* Bb = (const u16*)Bv;
  const float* Bf = (const float*)Bv;
  const size_t arow = (size_t)bx * 64 + ar;
  const size_t brow = (size_t)by * BN + br;
  const int kchunk = (SPLITK > 1) ? K / SPLITK : K;
  const int kstart = (SPLITK > 1) ? bz * kchunk : 0;
  int aw[2], bw[CB];
#pragma unroll
  for (int j = 0; j < 2; ++j) aw[j] = ar * 64 + (((2 * (t & 3) + j) ^ (ar & 7)) << 3);
#pragma unroll
  for (int j = 0; j < CB; ++j) bw[j] = br * 64 + ((((t % TPR) * CB + j) ^ (br & 7)) << 3);

  float sa = 0.f, sa2 = 0.f;
  f32x4 acc[MT][4];
#pragma unroll
  for (int i = 0; i < MT; ++i)
#pragma unroll
    for (int j = 0; j < 4; ++j) acc[i][j] = (f32x4){0.f, 0.f, 0.f, 0.f};

  f32x4 araw[4]; uint4 aS[2];
  f32x4 braw[2 * CB]; uint4 bS[CB];

  auto loadA = [&](int k0) {
    if (AF32) {
      const f32x4* p = (const f32x4*)&Af[arow * K + kstart + k0 + ac];
#pragma unroll
      for (int i = 0; i < 4; ++i) araw[i] = p[i];
    } else {
      const uint4* p = (const uint4*)&Ab[arow * K + kstart + k0 + ac];
      aS[0] = p[0]; aS[1] = p[1];
    }
  };
  auto loadB = [&](int k0) {
    if (BF32) {
      const f32x4* p = (const f32x4*)&Bf[brow * K + kstart + k0 + bc];
#pragma unroll
      for (int i = 0; i < 2 * CB; ++i) braw[i] = p[i];
    } else {
      const uint4* p = (const uint4*)&Bb[brow * K + kstart + k0 + bc];
#pragma unroll
      for (int i = 0; i < CB; ++i) bS[i] = p[i];
    }
  };
  auto storeAB = [&](int buf) {
    if (AF32) {
      if (EPI == 4) {
#pragma unroll
        for (int i = 0; i < 4; ++i)
#pragma unroll
          for (int j = 0; j < 4; ++j) { sa += araw[i][j]; sa2 += araw[i][j] * araw[i][j]; }
      }
      aS[0] = pack8(araw[0], araw[1]);
      aS[1] = pack8(araw[2], araw[3]);
    }
    if (BF32) {
#pragma unroll
      for (int i = 0; i < CB; ++i) bS[i] = pack8(braw[2 * i], braw[2 * i + 1]);
    }
    *(uint4*)&aT[buf][aw[0]] = aS[0];
    *(uint4*)&aT[buf][aw[1]] = aS[1];
#pragma unroll
    for (int i = 0; i < CB; ++i) *(uint4*)&bT[buf][bw[i]] = bS[i];
  };
  auto compute = [&](int buf) {
    bf16x8 af[MT][2], bfr[4][2];
#pragma unroll
    for (int mt = 0; mt < MT; ++mt) {
      int r = wm + mt * 16 + lcol;
#pragma unroll
      for (int kk = 0; kk < 2; ++kk)
        af[mt][kk] = *(const bf16x8*)&aT[buf][r * 64 + (((kk * 4 + quad) ^ (r & 7)) << 3)];
    }
#pragma unroll
    for (int nt = 0; nt < 4; ++nt) {
      int r = wn + nt * 16 + lcol;
#pragma unroll
      for (int kk = 0; kk < 2; ++kk)
        bfr[nt][kk] = *(const bf16x8*)&bT[buf][r * 64 + (((kk * 4 + quad) ^ (r & 7)) << 3)];
    }
#pragma unroll
    for (int kk = 0; kk < 2; ++kk)
#pragma unroll
      for (int mt = 0; mt < MT; ++mt)
#pragma unroll
        for (int nt = 0; nt < 4; ++nt)
          acc[mt][nt] = __builtin_amdgcn_mfma_f32_16x16x32_bf16(af[mt][kk], bfr[nt][kk], acc[mt][nt], 0, 0, 0);
  };

  const int nk = kchunk >> 6;
  loadA(0); loadB(0);
  storeAB(0);
  phase_barrier();
  int cur = 0;
  for (int kt = 0; kt < nk; ++kt) {
    if (kt + 1 < nk) { loadA((kt + 1) << 6); loadB((kt + 1) << 6); }
    compute(cur);
    if (kt + 1 < nk) storeAB(cur ^ 1);
    phase_barrier();
    cur ^= 1;
  }

  if (EPI == 4) {
    float s = sa, s2 = sa2;
    s += __shfl_xor(s, 1, 64);
    s += __shfl_xor(s, 2, 64);
    s2 += __shfl_xor(s2, 1, 64);
    s2 += __shfl_xor(s2, 2, 64);
    if ((t & 3) == 0) {
      float inv_n = 1.0f / (float)K;
      float mean = s * inv_n;
      float var = fmaxf(s2 * inv_n - mean * mean, 0.f);
      float rstd = rsqrtf(var + 1e-5f);
      rstd_s[ar] = rstd;
      mrstd_s[ar] = mean * rstd;
    }
    __syncthreads();
  }
  u16* Cb = (u16*)Cv;
  float* Cf = (float*)Cv;
  if (SPLITK > 1) Cf += (size_t)bz * (size_t)M * (size_t)N;
#pragma unroll
  for (int mt = 0; mt < MT; ++mt) {
#pragma unroll
    for (int nt = 0; nt < 4; ++nt) {
#pragma unroll
      for (int r = 0; r < 4; ++r) {
        int lrow = wm + mt * 16 + quad * 4 + r;
        int row = bx * 64 + lrow;
        int col = by * BN + wn + nt * 16 + lcol;
        float v = acc[mt][nt][r];
        if (EPI == 1 || EPI == 2 || EPI == 3) v += bias[col];
        if (EPI == 2) v = 0.5f * v * (1.f + erff(v * 0.70710678118f));
        if (EPI == 3) v += residf[(size_t)row * N + col];
        if (EPI == 4) v = rstd_s[lrow] * v - mrstd_s[lrow] * ucol[col] + wcol[col] + bias[col];
        size_t idx = (size_t)row * N + col;
        if (OUTF32) Cf[idx] = v; else Cb[idx] = f2b(v);
      }
    }
  }
}

// ---------------- split-K merge for W2: out = p0 + p1 + h + b2 ----------------
__global__ __launch_bounds__(256) void w2_merge(const float* __restrict__ part,
                                                const float* __restrict__ hf,
                                                const float* __restrict__ b2,
                                                float* __restrict__ out) {
  int idx = blockIdx.x * 256 + threadIdx.x;  // f32x4 index, 2048*768/4 total
  f32x4 p0 = ((const f32x4*)part)[idx];
  f32x4 p1 = ((const f32x4*)part)[idx + 393216];
  f32x4 h = ((const f32x4*)hf)[idx];
  f32x4 bb = ((const f32x4*)b2)[idx % 192];
  f32x4 o;
#pragma unroll
  for (int i = 0; i < 4; ++i) o[i] = p0[i] + p1[i] + h[i] + bb[i];
  ((f32x4*)out)[idx] = o;
}

// ---------------- flash attention, MQA (NKV=1), HD=64, no-max softmax, j-split=2 ----------------
__global__ __launch_bounds__(256) void attn_kernel(const u16* __restrict__ qbuf,
                                                   const u16* __restrict__ kvbuf,
                                                   const u16* __restrict__ VT,
                                                   float* __restrict__ Opart,
                                                   float* __restrict__ lpart) {
  __shared__ __align__(16) u16 k_lds[64 * 72];      // K[j][d]
  __shared__ __align__(16) u16 vt_lds[64 * 72];     // V^T[d][j]
  __shared__ __align__(16) u16 p_lds[4 * 16 * 72];  // per-wave P
  // XCD-chunked swizzle: colocate all 48 blocks of a (b,s) pair per XCD (nwg=768)
  int lid = ((int)blockIdx.z * 12 + (int)blockIdx.y) * 4 + (int)blockIdx.x;
  int wid = (lid & 7) * 96 + (lid >> 3);
  int bi = wid & 3;            // i-tile
  int h = (wid >> 2) % 12;     // head
  int z = wid / 48;            // b*2+s
  int b = z >> 1, s = z & 1;
  int t = threadIdx.x;
  int wave = t >> 6, lane = t & 63, quad = lane >> 4, lcol = lane & 15;
  int i0 = bi * 64 + wave * 16;
  const u16* qrow = qbuf + ((size_t)(b * 256 + i0 + lcol) * 768 + h * 64 + quad * 8);
  bf16x8 qf0 = *(const bf16x8*)qrow;
  bf16x8 qf1 = *(const bf16x8*)(qrow + 32);
  float l_r[4] = {0.f, 0.f, 0.f, 0.f};
  f32x4 oacc[4];
#pragma unroll
  for (int nt = 0; nt < 4; ++nt) oacc[nt] = (f32x4){0.f, 0.f, 0.f, 0.f};
  int sr = t >> 2, sc = (t & 3) * 16;
  const u16* kbase = kvbuf + ((size_t)b * 4096) * 128;
  const u16* vtbase = VT + (size_t)b * 64 * 4096;
  u16* pw = &p_lds[wave * 16 * 72];

  for (int jt = 0; jt < 32; ++jt) {
    int j0 = s * 2048 + jt * 64;
    const u16* krow = kbase + (size_t)(j0 + sr) * 128 + sc;
    *(uint4*)&k_lds[sr * 72 + sc] = *(const uint4*)(krow);
    *(uint4*)&k_lds[sr * 72 + sc + 8] = *(const uint4*)(krow + 8);
    const u16* vrow = vtbase + (size_t)sr * 4096 + j0 + sc;
    *(uint4*)&vt_lds[sr * 72 + sc] = *(const uint4*)(vrow);
    *(uint4*)&vt_lds[sr * 72 + sc + 8] = *(const uint4*)(vrow + 8);
    __syncthreads();

    f32x4 sc4[4];
#pragma unroll
    for (int nt = 0; nt < 4; ++nt) sc4[nt] = (f32x4){0.f, 0.f, 0.f, 0.f};
#pragma unroll
    for (int nt = 0; nt < 4; ++nt) {
      bf16x8 kb0 = *(const bf16x8*)&k_lds[(nt * 16 + lcol) * 72 + quad * 8];
      bf16x8 kb1 = *(const bf16x8*)&k_lds[(nt * 16 + lcol) * 72 + 32 + quad * 8];
      sc4[nt] = __builtin_amdgcn_mfma_f32_16x16x32_bf16(qf0, kb0, sc4[nt], 0, 0, 0);
      sc4[nt] = __builtin_amdgcn_mfma_f32_16x16x32_bf16(qf1, kb1, sc4[nt], 0, 0, 0);
    }
#pragma unroll
    for (int r = 0; r < 4; ++r) {
      float rsum = 0.f;
#pragma unroll
      for (int nt = 0; nt < 4; ++nt) {
        float p = __expf(sc4[nt][r] * 0.125f);
        sc4[nt][r] = p;
        rsum += p;
      }
      rsum += __shfl_xor(rsum, 1, 64);
      rsum += __shfl_xor(rsum, 2, 64);
      rsum += __shfl_xor(rsum, 4, 64);
      rsum += __shfl_xor(rsum, 8, 64);
      l_r[r] += rsum;
#pragma unroll
      for (int nt = 0; nt < 4; ++nt) pw[(quad * 4 + r) * 72 + nt * 16 + lcol] = f2b(sc4[nt][r]);
    }
#pragma unroll
    for (int ks = 0; ks < 2; ++ks) {
      bf16x8 pa = *(const bf16x8*)&pw[lcol * 72 + ks * 32 + quad * 8];
#pragma unroll
      for (int nt = 0; nt < 4; ++nt) {
        bf16x8 vb = *(const bf16x8*)&vt_lds[(nt * 16 + lcol) * 72 + ks * 32 + quad * 8];
        oacc[nt] = __builtin_amdgcn_mfma_f32_16x16x32_bf16(pa, vb, oacc[nt], 0, 0, 0);
      }
    }
    __syncthreads();
  }
  size_t base = ((size_t)z * 12 + h) * 256;
#pragma unroll
  for (int r = 0; r < 4; ++r) {
    int row = bi * 64 + wave * 16 + quad * 4 + r;
#pragma unroll
    for (int nt = 0; nt < 4; ++nt)
      Opart[(base + row) * 64 + nt * 16 + lcol] = oacc[nt][r];
    if (lcol == 0) lpart[base + row] = l_r[r];
  }
}

// ---------------- merge j-split partials -> attn_o bf16 ----------------
__global__ __launch_bounds__(256) void attn_merge(const float* __restrict__ Opart,
                                                  const float* __restrict__ lpart,
                                                  u16* __restrict__ attn_o) {
  int row = blockIdx.x;                      // 0..2047
  int col = blockIdx.y * 256 + threadIdx.x;  // 0..767
  int b = row >> 8, i = row & 255, h = col >> 6, d = col & 63;
  size_t i0 = (((size_t)(b * 2 + 0) * 12 + h) * 256 + i);
  size_t i1 = (((size_t)(b * 2 + 1) * 12 + h) * 256 + i);
  float o = Opart[i0 * 64 + d] + Opart[i1 * 64 + d];
  float l = lpart[i0] + lpart[i1];
  attn_o[(size_t)row * 768 + col] = f2b(o / l);
}

// ---------------- launch ----------------
extern "C" void kernel_launch(void* const* d_in, const int* in_sizes, int n_in, void* d_out,
                              int out_size, void* d_ws, size_t ws_size, hipStream_t stream) {
  (void)in_sizes; (void)n_in; (void)out_size; (void)ws_size;
  const float* hs = (const float*)d_in[0];
  const float* imgf = (const float*)d_in[1];
  const float* ln_img_g = (const float*)d_in[2];
  const float* ln_img_b = (const float*)d_in[3];
  const float* W_bottle = (const float*)d_in[4];
  const float* ln_h_g = (const float*)d_in[5];
  const float* ln_h_b = (const float*)d_in[6];
  const float* Wq = (const float*)d_in[7];
  const float* bq = (const float*)d_in[8];
  const float* Wkv = (const float*)d_in[9];
  const float* bkv = (const float*)d_in[10];
  const float* Wo = (const float*)d_in[11];
  const float* bo = (const float*)d_in[12];
  const float* ln_ao_g = (const float*)d_in[13];
  const float* ln_ao_b = (const float*)d_in[14];
  const float* gatep = (const float*)d_in[15];
  const float* ln_f_g = (const float*)d_in[16];
  const float* ln_f_b = (const float*)d_in[17];
  const float* W1 = (const float*)d_in[18];
  const float* b1 = (const float*)d_in[19];
  const float* W2 = (const float*)d_in[20];
  const float* b2 = (const float*)d_in[21];

  char* sc = (char*)d_ws;
  auto alloc = [&](size_t bytes) {
    char* p = sc;
    sc += (bytes + 63) & ~(size_t)63;
    return p;
  };
  u16* WTq = (u16*)alloc(768 * 768 * 2);
  u16* WTo = (u16*)alloc(768 * 768 * 2);
  u16* WT1 = (u16*)alloc(3072 * 768 * 2);
  u16* WT2 = (u16*)alloc(768 * 3072 * 2);
  u16* WkvT = (u16*)alloc(128 * 768 * 2);
  u16* WcT = (u16*)alloc(128 * 1024 * 2);
  u16* WgT = (u16*)alloc(128 * 1024 * 2);
  float* ucol = (float*)alloc(128 * 4);
  float* wcol = (float*)alloc(128 * 4);
  u16* kvb = (u16*)alloc((size_t)32768 * 128 * 2);
  u16* VT = (u16*)alloc((size_t)8 * 64 * 4096 * 2);
  u16* qin = (u16*)alloc(2048 * 768 * 2);
  u16* qb = (u16*)alloc(2048 * 768 * 2);
  u16* attn_o = (u16*)alloc(2048 * 768 * 2);
  u16* ao = (u16*)alloc(2048 * 768 * 2);
  u16* hbuf = (u16*)alloc(2048 * 768 * 2);
  float* hf32 = (float*)alloc(2048 * 768 * 4);
  u16* ffin = (u16*)alloc(2048 * 768 * 2);
  u16* actb = (u16*)alloc((size_t)2048 * 3072 * 2);
  float* Opart = (float*)alloc((size_t)16 * 12 * 256 * 64 * 4);  // reused as W2 split-K partials
  float* lpart = (float*)alloc((size_t)16 * 12 * 256 * 4);

  // weight transposes (f32 -> bf16, (N,K) layout)
  transpose_f2b<<<dim3(24, 24), 256, 0, stream>>>(Wq, WTq, 768, 768);
  transpose_f2b<<<dim3(24, 24), 256, 0, stream>>>(Wo, WTo, 768, 768);
  transpose_f2b<<<dim3(96, 24), 256, 0, stream>>>(W1, WT1, 768, 3072);
  transpose_f2b<<<dim3(24, 96), 256, 0, stream>>>(W2, WT2, 3072, 768);
  transpose_f2b<<<dim3(4, 24), 256, 0, stream>>>(Wkv, WkvT, 768, 128);

  // WcT[n,k] = sum_j WkvT[n,j] * W_bottle[k,j]   (B is f32)
  gemm_bt<128, 1, false, true, 0, false><<<dim3(2, 8), 256, 0, stream>>>(
      WkvT, W_bottle, nullptr, nullptr, nullptr, nullptr, WcT, 128, 1024, 768);
  prep_wg<<<32, 256, 0, stream>>>(WcT, ln_img_g, ln_img_b, WgT, ucol, wcol);
  // kv = rstd*(x@Wg) - mrstd*u + w + bkv  (A f32, fused LN stats)
  gemm_bt<128, 1, true, false, 4, false><<<dim3(512, 1), 256, 0, stream>>>(
      imgf, WgT, bkv, nullptr, ucol, wcol, kvb, 32768, 128, 1024);
  // V^T per batch
  vt_kernel<<<dim3(128, 2, 8), 256, 0, stream>>>(kvb, VT);
  // q path
  row_ln<true, false><<<512, 256, 0, stream>>>(hs, ln_h_g, ln_h_b, qin, nullptr, nullptr, nullptr);
  gemm_bt<64, 1, false, false, 1, false><<<dim3(32, 12), 256, 0, stream>>>(
      qin, WTq, bq, nullptr, nullptr, nullptr, qb, 2048, 768, 768);
  // attention (j-split=2) + merge
  attn_kernel<<<dim3(4, 12, 16), 256, 0, stream>>>(qb, kvb, VT, Opart, lpart);
  attn_merge<<<dim3(2048, 3), 256, 0, stream>>>(Opart, lpart, attn_o);
  // out proj
  gemm_bt<64, 1, false, false, 1, false><<<dim3(32, 12), 256, 0, stream>>>(
      attn_o, WTo, bo, nullptr, nullptr, nullptr, ao, 2048, 768, 768);
  // h = hs + sigmoid(gate)*LN(ao)  (dual bf16 + f32)
  row_ln<false, true><<<512, 256, 0, stream>>>(ao, ln_ao_g, ln_ao_b, hbuf, hf32, hs, gatep);
  // ffn_in = LN(h)  (from f32 h)
  row_ln<true, false><<<512, 256, 0, stream>>>(hf32, ln_f_g, ln_f_b, ffin, nullptr, nullptr, nullptr);
  // act = gelu(ffn_in @ W1 + b1)
  gemm_bt<128, 1, false, false, 2, false><<<dim3(32, 24), 256, 0, stream>>>(
      ffin, WT1, b1, nullptr, nullptr, nullptr, actb, 2048, 3072, 768);
  // W2 split-K=2: partials into Opart (free after attn_merge), then merge
  gemm_bt<64, 2, false, false, 0, true><<<dim3(32, 12, 2), 256, 0, stream>>>(
      actb, WT2, nullptr, nullptr, nullptr, nullptr, Opart, 2048, 768, 3072);
  w2_merge<<<1536, 256, 0, stream>>>(Opart, hf32, b2, (float*)d_out);
}

// Round 4
// 612.416 us; speedup vs baseline: 1.0826x; 1.0388x over previous
//
#include <hip/hip_runtime.h>
#include <cstdint>

typedef unsigned short u16;
typedef __bf16 bf16_t;
typedef bf16_t bf16x8 __attribute__((ext_vector_type(8)));
typedef float f32x4 __attribute__((ext_vector_type(4)));

__device__ __forceinline__ float b2f(u16 v) {
  union { uint32_t u; float f; } c; c.u = ((uint32_t)v) << 16; return c.f;
}
__device__ __forceinline__ u16 f2b(float f) {
  union { float f; uint32_t u; } c; c.f = f;
  uint32_t lsb = (c.u >> 16) & 1u;
  return (u16)((c.u + 0x7fffu + lsb) >> 16);
}
__device__ __forceinline__ uint4 pack8(f32x4 a, f32x4 b) {
  union { uint4 v; u16 s[8]; } r;
  r.s[0] = f2b(a[0]); r.s[1] = f2b(a[1]); r.s[2] = f2b(a[2]); r.s[3] = f2b(a[3]);
  r.s[4] = f2b(b[0]); r.s[5] = f2b(b[1]); r.s[6] = f2b(b[2]); r.s[7] = f2b(b[3]);
  return r.v;
}
// raw barrier: no vmcnt drain
__device__ __forceinline__ void phase_barrier() {
  asm volatile("s_waitcnt lgkmcnt(0)" ::: "memory");
  __builtin_amdgcn_s_barrier();
  asm volatile("" ::: "memory");
}
// bijective chunked XCD swizzle (m204)
__device__ __forceinline__ int xcd_swizzle(int lid, int nwg) {
  int q = nwg >> 3, r = nwg & 7, x = lid & 7, s = lid >> 3;
  return (x < r ? x * (q + 1) : r * (q + 1) + (x - r) * q) + s;
}

// ---------------- transpose f32 (R,C) -> bf16 (C,R) ----------------
__global__ __launch_bounds__(256) void transpose_f2b(const float* __restrict__ in,
                                                     u16* __restrict__ out, int R, int C) {
  __shared__ __align__(16) u16 tile[32][33];
  int tx = threadIdx.x & 31, ty = threadIdx.x >> 5;
  int c0 = blockIdx.x * 32, r0 = blockIdx.y * 32;
#pragma unroll
  for (int i = 0; i < 4; ++i) {
    int r = r0 + ty + i * 8, c = c0 + tx;
    if (r < R && c < C) tile[ty + i * 8][tx] = f2b(in[(size_t)r * C + c]);
  }
  __syncthreads();
#pragma unroll
  for (int i = 0; i < 4; ++i) {
    int oc = c0 + ty + i * 8, orr = r0 + tx;
    if (oc < C && orr < R) out[(size_t)oc * R + orr] = tile[tx][ty + i * 8];
  }
}

// ------- WgT[n,k]=g[k]*WT[n,k]; u[n]=sum g*W; w[n]=sum b*W  (generic K) -------
__global__ __launch_bounds__(256) void prep_wg(const u16* __restrict__ WT, const float* __restrict__ g,
                                               const float* __restrict__ b, u16* __restrict__ WgT,
                                               float* __restrict__ ucol, float* __restrict__ wcol,
                                               int K) {
  int n = blockIdx.x * 4 + (threadIdx.x >> 6);
  int lane = threadIdx.x & 63;
  const u16* src = WT + (size_t)n * K;
  u16* dst = WgT + (size_t)n * K;
  float su = 0.f, sw = 0.f;
  for (int k = lane; k < K; k += 64) {
    float wc = b2f(src[k]);
    float wg = g[k] * wc;
    dst[k] = f2b(wg);
    su += wg;
    sw += b[k] * wc;
  }
#pragma unroll
  for (int off = 32; off >= 1; off >>= 1) {
    su += __shfl_xor(su, off, 64);
    sw += __shfl_xor(sw, off, 64);
  }
  if (lane == 0) { ucol[n] = su; wcol[n] = sw; }
}

// ---------------- h = hs + sigmoid(gate)*LN(ao)  (f32 out only) ----------------
__global__ __launch_bounds__(256) void ln_res(const u16* __restrict__ ao, const float* __restrict__ g,
                                              const float* __restrict__ bta,
                                              const float* __restrict__ hs,
                                              const float* __restrict__ gatep,
                                              float* __restrict__ hf) {
  int row = blockIdx.x * 4 + (threadIdx.x >> 6);
  int lane = threadIdx.x & 63;
  const u16* xb = ao + (size_t)row * 768;
  float v[12];
#pragma unroll
  for (int it = 0; it < 3; ++it) {
    int c = (lane + it * 64) * 4;
    uint2 d = *(const uint2*)(xb + c);
    v[it * 4 + 0] = b2f(d.x & 0xffff); v[it * 4 + 1] = b2f(d.x >> 16);
    v[it * 4 + 2] = b2f(d.y & 0xffff); v[it * 4 + 3] = b2f(d.y >> 16);
  }
  float s = 0.f, s2 = 0.f;
#pragma unroll
  for (int i = 0; i < 12; ++i) { s += v[i]; s2 += v[i] * v[i]; }
#pragma unroll
  for (int off = 32; off >= 1; off >>= 1) {
    s += __shfl_xor(s, off, 64);
    s2 += __shfl_xor(s2, off, 64);
  }
  float inv_n = 1.0f / 768.f;
  float mean = s * inv_n;
  float var = fmaxf(s2 * inv_n - mean * mean, 0.f);
  float rstd = rsqrtf(var + 1e-5f);
  float gate = 1.f / (1.f + __expf(-gatep[0]));
#pragma unroll
  for (int it = 0; it < 3; ++it) {
    int c = (lane + it * 64) * 4;
    const float* rr = hs + (size_t)row * 768 + c;
    float o[4];
#pragma unroll
    for (int i = 0; i < 4; ++i)
      o[i] = rr[i] + gate * ((v[it * 4 + i] - mean) * rstd * g[c + i] + bta[c + i]);
    *(f32x4*)(hf + (size_t)row * 768 + c) = (f32x4){o[0], o[1], o[2], o[3]};
  }
}

// ---------------- MFMA GEMM body: C = A(MxK)*BT(NxK)^T ----------------
// AMODE: 0 bf16 A | 1 f32 A | 2 merge-A (Opart + lpart via aux)
// EPI: 0 none | 1 +bias | 2 +bias,gelu | 3 +bias+resid_f32(aux) | 4 LN-fold+bias | 5 LN-fold+bias+gelu
// VTOUT: kv-only — C is K-only [M][64] bf16; v-half transposed to VTout per batch.
template <int BN, int SPLITK, int AMODE, bool BF32, int EPI, bool OUTF32, bool VTOUT>
__device__ __forceinline__ void gemm_body(const void* __restrict__ Av, const void* __restrict__ Bv,
                                          const float* __restrict__ bias,
                                          const float* __restrict__ aux,
                                          const float* __restrict__ ucol,
                                          const float* __restrict__ wcol,
                                          void* __restrict__ Cv, u16* __restrict__ VTout,
                                          int M, int N, int K) {
  constexpr int WN = BN / 64;
  constexpr int WM = 4 / WN;
  constexpr int MT = 64 / (16 * WM);
  constexpr int TPR = 256 / BN;
  constexpr int CB = 8 / TPR;
  __shared__ __align__(16) u16 aT[2][64 * 64];
  __shared__ __align__(16) u16 bT[2][BN * 64];
  __shared__ float rstd_s[EPI >= 4 ? 64 : 1];
  __shared__ float mrstd_s[EPI >= 4 ? 64 : 1];
  __shared__ __align__(16) u16 vtile[VTOUT ? 64 * 72 : 1];
  // XCD-chunked remap, N-fast within chunk (A-panel reuse in L2)
  int gx = gridDim.x, gy = gridDim.y;
  int nwg = gx * gy * (int)gridDim.z;
  int lid = ((int)blockIdx.z * gy + (int)blockIdx.y) * gx + (int)blockIdx.x;
  int wid = xcd_swizzle(lid, nwg);
  int bz = wid / (gx * gy);
  int rem = wid - bz * (gx * gy);
  int bx = rem / gy;
  int by = rem - bx * gy;

  int t = threadIdx.x, lane = t & 63, wave = t >> 6;
  int quad = lane >> 4, lcol = lane & 15;
  int wm = (wave / WN) * (16 * MT), wn = (wave % WN) * 64;
  int ar = t >> 2, ac = (t & 3) * 16;
  int br = t / TPR, bc = (t % TPR) * (64 / TPR);
  const u16* Ab = (const u16*)Av;
  const float* Af = (const float*)Av;
  const u16* Bb = (const u16*)Bv;
  const float* Bf = (const float*)Bv;
  const size_t arow = (size_t)bx * 64 + ar;
  const size_t brow = (size_t)by * BN + br;
  const int kchunk = (SPLITK > 1) ? K / SPLITK : K;
  const int kstart = (SPLITK > 1) ? bz * kchunk : 0;
  int aw[2], bw[CB];
#pragma unroll
  for (int j = 0; j < 2; ++j) aw[j] = ar * 64 + (((2 * (t & 3) + j) ^ (ar & 7)) << 3);
#pragma unroll
  for (int j = 0; j < CB; ++j) bw[j] = br * 64 + ((((t % TPR) * CB + j) ^ (br & 7)) << 3);

  float sa = 0.f, sa2 = 0.f;
  f32x4 acc[MT][4];
#pragma unroll
  for (int i = 0; i < MT; ++i)
#pragma unroll
    for (int j = 0; j < 4; ++j) acc[i][j] = (f32x4){0.f, 0.f, 0.f, 0.f};

  f32x4 araw[4]; uint4 aS[2];
  f32x4 braw[2 * CB]; uint4 bS[CB];

  auto loadA = [&](int k0) {
    if (AMODE == 1) {
      const f32x4* p = (const f32x4*)&Af[arow * K + kstart + k0 + ac];
#pragma unroll
      for (int i = 0; i < 4; ++i) araw[i] = p[i];
    } else if (AMODE == 2) {
      // merged attention output: A[row][c] = (Op0+Op1)/(l0+l1), c -> (h,d)
      int c0 = k0 + ac;
      int hh = c0 >> 6, dd = c0 & 63;
      int bb = (int)(arow >> 8), ii = (int)(arow & 255);
      size_t base0 = ((size_t)((bb * 2 + 0) * 12 + hh) * 256 + (size_t)ii);
      size_t base1 = ((size_t)((bb * 2 + 1) * 12 + hh) * 256 + (size_t)ii);
      const f32x4* p0 = (const f32x4*)(Af + base0 * 64 + dd);
      const f32x4* p1 = (const f32x4*)(Af + base1 * 64 + dd);
      float rl = 1.f / (aux[base0] + aux[base1]);
#pragma unroll
      for (int i = 0; i < 4; ++i) {
        f32x4 s0 = p0[i], s1 = p1[i];
#pragma unroll
        for (int j = 0; j < 4; ++j) araw[i][j] = (s0[j] + s1[j]) * rl;
      }
    } else {
      const uint4* p = (const uint4*)&Ab[arow * K + kstart + k0 + ac];
      aS[0] = p[0]; aS[1] = p[1];
    }
  };
  auto loadB = [&](int k0) {
    if (BF32) {
      const f32x4* p = (const f32x4*)&Bf[brow * K + kstart + k0 + bc];
#pragma unroll
      for (int i = 0; i < 2 * CB; ++i) braw[i] = p[i];
    } else {
      const uint4* p = (const uint4*)&Bb[brow * K + kstart + k0 + bc];
#pragma unroll
      for (int i = 0; i < CB; ++i) bS[i] = p[i];
    }
  };
  auto storeAB = [&](int buf) {
    if (AMODE != 0) {
      if (AMODE == 1 && EPI >= 4) {
#pragma unroll
        for (int i = 0; i < 4; ++i)
#pragma unroll
          for (int j = 0; j < 4; ++j) { sa += araw[i][j]; sa2 += araw[i][j] * araw[i][j]; }
      }
      aS[0] = pack8(araw[0], araw[1]);
      aS[1] = pack8(araw[2], araw[3]);
    }
    if (BF32) {
#pragma unroll
      for (int i = 0; i < CB; ++i) bS[i] = pack8(braw[2 * i], braw[2 * i + 1]);
    }
    *(uint4*)&aT[buf][aw[0]] = aS[0];
    *(uint4*)&aT[buf][aw[1]] = aS[1];
#pragma unroll
    for (int i = 0; i < CB; ++i) *(uint4*)&bT[buf][bw[i]] = bS[i];
  };
  auto compute = [&](int buf) {
    bf16x8 af[MT][2], bfr[4][2];
#pragma unroll
    for (int mt = 0; mt < MT; ++mt) {
      int r = wm + mt * 16 + lcol;
#pragma unroll
      for (int kk = 0; kk < 2; ++kk)
        af[mt][kk] = *(const bf16x8*)&aT[buf][r * 64 + (((kk * 4 + quad) ^ (r & 7)) << 3)];
    }
#pragma unroll
    for (int nt = 0; nt < 4; ++nt) {
      int r = wn + nt * 16 + lcol;
#pragma unroll
      for (int kk = 0; kk < 2; ++kk)
        bfr[nt][kk] = *(const bf16x8*)&bT[buf][r * 64 + (((kk * 4 + quad) ^ (r & 7)) << 3)];
    }
#pragma unroll
    for (int kk = 0; kk < 2; ++kk)
#pragma unroll
      for (int mt = 0; mt < MT; ++mt)
#pragma unroll
        for (int nt = 0; nt < 4; ++nt)
          acc[mt][nt] = __builtin_amdgcn_mfma_f32_16x16x32_bf16(af[mt][kk], bfr[nt][kk], acc[mt][nt], 0, 0, 0);
  };

  const int nk = kchunk >> 6;
  loadA(0); loadB(0);
  storeAB(0);
  phase_barrier();
  int cur = 0;
  for (int kt = 0; kt < nk; ++kt) {
    if (kt + 1 < nk) { loadA((kt + 1) << 6); loadB((kt + 1) << 6); }
    compute(cur);
    if (kt + 1 < nk) storeAB(cur ^ 1);
    phase_barrier();
    cur ^= 1;
  }

  if (EPI >= 4) {
    float s = sa, s2 = sa2;
    s += __shfl_xor(s, 1, 64);
    s += __shfl_xor(s, 2, 64);
    s2 += __shfl_xor(s2, 1, 64);
    s2 += __shfl_xor(s2, 2, 64);
    if ((t & 3) == 0) {
      float inv_n = 1.0f / (float)K;
      float mean = s * inv_n;
      float var = fmaxf(s2 * inv_n - mean * mean, 0.f);
      float rstd = rsqrtf(var + 1e-5f);
      rstd_s[ar] = rstd;
      mrstd_s[ar] = mean * rstd;
    }
    __syncthreads();
  }

  if (VTOUT) {
    // kv epilogue: cols 0..63 -> kb[M][64]; cols 64..127 -> LDS transpose -> VT[b][d][j]
    u16* kb = (u16*)Cv;
#pragma unroll
    for (int mt = 0; mt < MT; ++mt) {
#pragma unroll
      for (int nt = 0; nt < 4; ++nt) {
#pragma unroll
        for (int r = 0; r < 4; ++r) {
          int lrow = wm + mt * 16 + quad * 4 + r;
          int row = bx * 64 + lrow;
          int col = wn + nt * 16 + lcol;
          float v = rstd_s[lrow] * acc[mt][nt][r] - mrstd_s[lrow] * ucol[col] + wcol[col] + bias[col];
          u16 hv = f2b(v);
          if (wn == 0) kb[(size_t)row * 64 + col] = hv;
          else vtile[(col - 64) * 72 + lrow] = hv;
        }
      }
    }
    __syncthreads();
    int dd = t >> 2, js = (t & 3) * 16;
    int bg = bx >> 6, j0g = (bx & 63) * 64;
    uint4 w0 = *(const uint4*)&vtile[dd * 72 + js];
    uint4 w1 = *(const uint4*)&vtile[dd * 72 + js + 8];
    u16* dst = VTout + ((size_t)bg * 64 + dd) * 4096 + j0g + js;
    *(uint4*)dst = w0;
    *(uint4*)(dst + 8) = w1;
    return;
  }

  u16* Cb = (u16*)Cv;
  float* Cf = (float*)Cv;
  if (SPLITK > 1) Cf += (size_t)bz * (size_t)M * (size_t)N;
#pragma unroll
  for (int mt = 0; mt < MT; ++mt) {
#pragma unroll
    for (int nt = 0; nt < 4; ++nt) {
#pragma unroll
      for (int r = 0; r < 4; ++r) {
        int lrow = wm + mt * 16 + quad * 4 + r;
        int row = bx * 64 + lrow;
        int col = by * BN + wn + nt * 16 + lcol;
        float v = acc[mt][nt][r];
        if (EPI == 1 || EPI == 2 || EPI == 3) v += bias[col];
        if (EPI >= 4) v = rstd_s[lrow] * v - mrstd_s[lrow] * ucol[col] + wcol[col] + bias[col];
        if (EPI == 2 || EPI == 5) v = 0.5f * v * (1.f + erff(v * 0.70710678118f));
        if (EPI == 3) v += aux[(size_t)row * N + col];
        size_t idx = (size_t)row * N + col;
        if (OUTF32) Cf[idx] = v; else Cb[idx] = f2b(v);
      }
    }
  }
}

// distinct names per call site (rocprof attribution)
#define GEMM_ARGS const void* Av, const void* Bv, const float* bias, const float* aux, \
                  const float* ucol, const float* wcol, void* Cv, u16* VTout, int M, int N, int K
__global__ __launch_bounds__(256) void gemm_wc(GEMM_ARGS) {
  gemm_body<128, 1, 0, true, 0, false, false>(Av, Bv, bias, aux, ucol, wcol, Cv, VTout, M, N, K);
}
__global__ __launch_bounds__(256) void gemm_kv(GEMM_ARGS) {
  gemm_body<128, 1, 1, false, 4, false, true>(Av, Bv, bias, aux, ucol, wcol, Cv, VTout, M, N, K);
}
__global__ __launch_bounds__(256) void gemm_q(GEMM_ARGS) {
  gemm_body<64, 1, 1, false, 4, false, false>(Av, Bv, bias, aux, ucol, wcol, Cv, VTout, M, N, K);
}
__global__ __launch_bounds__(256) void gemm_o(GEMM_ARGS) {
  gemm_body<64, 1, 2, false, 1, false, false>(Av, Bv, bias, aux, ucol, wcol, Cv, VTout, M, N, K);
}
__global__ __launch_bounds__(256) void gemm_w1(GEMM_ARGS) {
  gemm_body<128, 1, 1, false, 5, false, false>(Av, Bv, bias, aux, ucol, wcol, Cv, VTout, M, N, K);
}
__global__ __launch_bounds__(256) void gemm_w2(GEMM_ARGS) {
  gemm_body<64, 2, 0, false, 0, true, false>(Av, Bv, bias, aux, ucol, wcol, Cv, VTout, M, N, K);
}

// ---------------- split-K merge for W2: out = p0 + p1 + h + b2 ----------------
__global__ __launch_bounds__(256) void w2_merge(const float* __restrict__ part,
                                                const float* __restrict__ hf,
                                                const float* __restrict__ b2,
                                                float* __restrict__ out) {
  int idx = blockIdx.x * 256 + threadIdx.x;
  f32x4 p0 = ((const f32x4*)part)[idx];
  f32x4 p1 = ((const f32x4*)part)[idx + 393216];
  f32x4 h = ((const f32x4*)hf)[idx];
  f32x4 bb = ((const f32x4*)b2)[idx % 192];
  f32x4 o;
#pragma unroll
  for (int i = 0; i < 4; ++i) o[i] = p0[i] + p1[i] + h[i] + bb[i];
  ((f32x4*)out)[idx] = o;
}

// ---------------- flash attention, MQA (NKV=1), HD=64, no-max softmax, j-split=2 ----------------
// kb: [b*4096+j][64] bf16 keys; VT: [b][d][j] bf16 values^T
__global__ __launch_bounds__(256) void attn_kernel(const u16* __restrict__ qbuf,
                                                   const u16* __restrict__ kb,
                                                   const u16* __restrict__ VT,
                                                   float* __restrict__ Opart,
                                                   float* __restrict__ lpart) {
  __shared__ __align__(16) u16 k_lds[64 * 72];
  __shared__ __align__(16) u16 vt_lds[64 * 72];
  __shared__ __align__(16) u16 p_lds[4 * 16 * 72];
  int lid = ((int)blockIdx.z * 12 + (int)blockIdx.y) * 4 + (int)blockIdx.x;
  int wid = (lid & 7) * 96 + (lid >> 3);
  int bi = wid & 3;
  int h = (wid >> 2) % 12;
  int z = wid / 48;
  int b = z >> 1, s = z & 1;
  int t = threadIdx.x;
  int wave = t >> 6, lane = t & 63, quad = lane >> 4, lcol = lane & 15;
  int i0 = bi * 64 + wave * 16;
  const u16* qrow = qbuf + ((size_t)(b * 256 + i0 + lcol) * 768 + h * 64 + quad * 8);
  bf16x8 qf0 = *(const bf16x8*)qrow;
  bf16x8 qf1 = *(const bf16x8*)(qrow + 32);
  float l_r[4] = {0.f, 0.f, 0.f, 0.f};
  f32x4 oacc[4];
#pragma unroll
  for (int nt = 0; nt < 4; ++nt) oacc[nt] = (f32x4){0.f, 0.f, 0.f, 0.f};
  int sr = t >> 2, sc = (t & 3) * 16;
  const u16* kbase = kb + (size_t)b * 4096 * 64;
  const u16* vtbase = VT + (size_t)b * 64 * 4096;
  u16* pw = &p_lds[wave * 16 * 72];

  for (int jt = 0; jt < 32; ++jt) {
    int j0 = s * 2048 + jt * 64;
    const u16* krow = kbase + (size_t)(j0 + sr) * 64 + sc;
    *(uint4*)&k_lds[sr * 72 + sc] = *(const uint4*)(krow);
    *(uint4*)&k_lds[sr * 72 + sc + 8] = *(const uint4*)(krow + 8);
    const u16* vrow = vtbase + (size_t)sr * 4096 + j0 + sc;
    *(uint4*)&vt_lds[sr * 72 + sc] = *(const uint4*)(vrow);
    *(uint4*)&vt_lds[sr * 72 + sc + 8] = *(const uint4*)(vrow + 8);
    __syncthreads();

    f32x4 sc4[4];
#pragma unroll
    for (int nt = 0; nt < 4; ++nt) sc4[nt] = (f32x4){0.f, 0.f, 0.f, 0.f};
#pragma unroll
    for (int nt = 0; nt < 4; ++nt) {
      bf16x8 kb0 = *(const bf16x8*)&k_lds[(nt * 16 + lcol) * 72 + quad * 8];
      bf16x8 kb1 = *(const bf16x8*)&k_lds[(nt * 16 + lcol) * 72 + 32 + quad * 8];
      sc4[nt] = __builtin_amdgcn_mfma_f32_16x16x32_bf16(qf0, kb0, sc4[nt], 0, 0, 0);
      sc4[nt] = __builtin_amdgcn_mfma_f32_16x16x32_bf16(qf1, kb1, sc4[nt], 0, 0, 0);
    }
#pragma unroll
    for (int r = 0; r < 4; ++r) {
      float rsum = 0.f;
#pragma unroll
      for (int nt = 0; nt < 4; ++nt) {
        float p = __expf(sc4[nt][r] * 0.125f);
        sc4[nt][r] = p;
        rsum += p;
      }
      rsum += __shfl_xor(rsum, 1, 64);
      rsum += __shfl_xor(rsum, 2, 64);
      rsum += __shfl_xor(rsum, 4, 64);
      rsum += __shfl_xor(rsum, 8, 64);
      l_r[r] += rsum;
#pragma unroll
      for (int nt = 0; nt < 4; ++nt) pw[(quad * 4 + r) * 72 + nt * 16 + lcol] = f2b(sc4[nt][r]);
    }
#pragma unroll
    for (int ks = 0; ks < 2; ++ks) {
      bf16x8 pa = *(const bf16x8*)&pw[lcol * 72 + ks * 32 + quad * 8];
#pragma unroll
      for (int nt = 0; nt < 4; ++nt) {
        bf16x8 vb = *(const bf16x8*)&vt_lds[(nt * 16 + lcol) * 72 + ks * 32 + quad * 8];
        oacc[nt] = __builtin_amdgcn_mfma_f32_16x16x32_bf16(pa, vb, oacc[nt], 0, 0, 0);
      }
    }
    __syncthreads();
  }
  size_t base = ((size_t)z * 12 + h) * 256;
#pragma unroll
  for (int r = 0; r < 4; ++r) {
    int row = bi * 64 + wave * 16 + quad * 4 + r;
#pragma unroll
    for (int nt = 0; nt < 4; ++nt)
      Opart[(base + row) * 64 + nt * 16 + lcol] = oacc[nt][r];
    if (lcol == 0) lpart[base + row] = l_r[r];
  }
}

// ---------------- launch ----------------
extern "C" void kernel_launch(void* const* d_in, const int* in_sizes, int n_in, void* d_out,
                              int out_size, void* d_ws, size_t ws_size, hipStream_t stream) {
  (void)in_sizes; (void)n_in; (void)out_size; (void)ws_size;
  const float* hs = (const float*)d_in[0];
  const float* imgf = (const float*)d_in[1];
  const float* ln_img_g = (const float*)d_in[2];
  const float* ln_img_b = (const float*)d_in[3];
  const float* W_bottle = (const float*)d_in[4];
  const float* ln_h_g = (const float*)d_in[5];
  const float* ln_h_b = (const float*)d_in[6];
  const float* Wq = (const float*)d_in[7];
  const float* bq = (const float*)d_in[8];
  const float* Wkv = (const float*)d_in[9];
  const float* bkv = (const float*)d_in[10];
  const float* Wo = (const float*)d_in[11];
  const float* bo = (const float*)d_in[12];
  const float* ln_ao_g = (const float*)d_in[13];
  const float* ln_ao_b = (const float*)d_in[14];
  const float* gatep = (const float*)d_in[15];
  const float* ln_f_g = (const float*)d_in[16];
  const float* ln_f_b = (const float*)d_in[17];
  const float* W1 = (const float*)d_in[18];
  const float* b1 = (const float*)d_in[19];
  const float* W2 = (const float*)d_in[20];
  const float* b2 = (const float*)d_in[21];

  char* sc = (char*)d_ws;
  auto alloc = [&](size_t bytes) {
    char* p = sc;
    sc += (bytes + 63) & ~(size_t)63;
    return p;
  };
  u16* WTq = (u16*)alloc(768 * 768 * 2);
  u16* WTo = (u16*)alloc(768 * 768 * 2);
  u16* WT1 = (u16*)alloc(3072 * 768 * 2);
  u16* WT2 = (u16*)alloc(768 * 3072 * 2);
  u16* WkvT = (u16*)alloc(128 * 768 * 2);
  u16* WcT = (u16*)alloc(128 * 1024 * 2);
  u16* WgT = (u16*)alloc(128 * 1024 * 2);
  u16* WqgT = (u16*)alloc(768 * 768 * 2);
  u16* W1gT = (u16*)alloc(3072 * 768 * 2);
  float* ucol = (float*)alloc(128 * 4);
  float* wcol = (float*)alloc(128 * 4);
  float* uq = (float*)alloc(768 * 4);
  float* wq = (float*)alloc(768 * 4);
  float* u1 = (float*)alloc(3072 * 4);
  float* w1c = (float*)alloc(3072 * 4);
  u16* kb = (u16*)alloc((size_t)32768 * 64 * 2);
  u16* VT = (u16*)alloc((size_t)8 * 64 * 4096 * 2);
  u16* qb = (u16*)alloc(2048 * 768 * 2);
  u16* ao = (u16*)alloc(2048 * 768 * 2);
  float* hf32 = (float*)alloc(2048 * 768 * 4);
  u16* actb = (u16*)alloc((size_t)2048 * 3072 * 2);
  float* Opart = (float*)alloc((size_t)16 * 12 * 256 * 64 * 4);  // also W2 split-K partials
  float* lpart = (float*)alloc((size_t)16 * 12 * 256 * 4);

  // weight transposes (f32 -> bf16, (N,K) layout)
  transpose_f2b<<<dim3(24, 24), 256, 0, stream>>>(Wq, WTq, 768, 768);
  transpose_f2b<<<dim3(24, 24), 256, 0, stream>>>(Wo, WTo, 768, 768);
  transpose_f2b<<<dim3(96, 24), 256, 0, stream>>>(W1, WT1, 768, 3072);
  transpose_f2b<<<dim3(24, 96), 256, 0, stream>>>(W2, WT2, 3072, 768);
  transpose_f2b<<<dim3(4, 24), 256, 0, stream>>>(Wkv, WkvT, 768, 128);

  // WcT[n,k] = sum_j WkvT[n,j] * W_bottle[k,j]
  gemm_wc<<<dim3(2, 8), 256, 0, stream>>>(WkvT, W_bottle, nullptr, nullptr, nullptr, nullptr,
                                          WcT, nullptr, 128, 1024, 768);
  // LN-fold weight preps
  prep_wg<<<32, 256, 0, stream>>>(WcT, ln_img_g, ln_img_b, WgT, ucol, wcol, 1024);
  prep_wg<<<192, 256, 0, stream>>>(WTq, ln_h_g, ln_h_b, WqgT, uq, wq, 768);
  prep_wg<<<768, 256, 0, stream>>>(WT1, ln_f_g, ln_f_b, W1gT, u1, w1c, 768);
  // kv (fused img-LN) -> kb (keys) + VT (values^T, fused transpose epilogue)
  gemm_kv<<<dim3(512, 1), 256, 0, stream>>>(imgf, WgT, bkv, nullptr, ucol, wcol,
                                            kb, VT, 32768, 128, 1024);
  // q = LN(hs) @ Wq + bq  (fused LN)
  gemm_q<<<dim3(32, 12), 256, 0, stream>>>(hs, WqgT, bq, nullptr, uq, wq,
                                           qb, nullptr, 2048, 768, 768);
  // attention (j-split=2)
  attn_kernel<<<dim3(4, 12, 16), 256, 0, stream>>>(qb, kb, VT, Opart, lpart);
  // out proj with fused j-split merge in A-load
  gemm_o<<<dim3(32, 12), 256, 0, stream>>>(Opart, WTo, bo, lpart, nullptr, nullptr,
                                           ao, nullptr, 2048, 768, 768);
  // h = hs + sigmoid(gate)*LN(ao)
  ln_res<<<512, 256, 0, stream>>>(ao, ln_ao_g, ln_ao_b, hs, gatep, hf32);
  // act = gelu(LN(h) @ W1 + b1)  (fused LN)
  gemm_w1<<<dim3(32, 24), 256, 0, stream>>>(hf32, W1gT, b1, nullptr, u1, w1c,
                                            actb, nullptr, 2048, 3072, 768);
  // W2 split-K=2 partials into Opart, then merge with h + b2
  gemm_w2<<<dim3(32, 12, 2), 256, 0, stream>>>(actb, WT2, nullptr, nullptr, nullptr, nullptr,
                                               Opart, nullptr, 2048, 768, 3072);
  w2_merge<<<1536, 256, 0, stream>>>(Opart, hf32, b2, (float*)d_out);
}

// Round 5
// 536.044 us; speedup vs baseline: 1.2368x; 1.1425x over previous
//
#include <hip/hip_runtime.h>
#include <cstdint>

typedef unsigned short u16;
typedef __bf16 bf16_t;
typedef bf16_t bf16x8 __attribute__((ext_vector_type(8)));
typedef float f32x4 __attribute__((ext_vector_type(4)));

__device__ __forceinline__ float b2f(u16 v) {
  union { uint32_t u; float f; } c; c.u = ((uint32_t)v) << 16; return c.f;
}
__device__ __forceinline__ u16 f2b(float f) {
  union { float f; uint32_t u; } c; c.f = f;
  uint32_t lsb = (c.u >> 16) & 1u;
  return (u16)((c.u + 0x7fffu + lsb) >> 16);
}
__device__ __forceinline__ uint4 pack8(f32x4 a, f32x4 b) {
  union { uint4 v; u16 s[8]; } r;
  r.s[0] = f2b(a[0]); r.s[1] = f2b(a[1]); r.s[2] = f2b(a[2]); r.s[3] = f2b(a[3]);
  r.s[4] = f2b(b[0]); r.s[5] = f2b(b[1]); r.s[6] = f2b(b[2]); r.s[7] = f2b(b[3]);
  return r.v;
}
// raw barrier: lgkm drain + s_barrier (no implicit vmcnt drain)
__device__ __forceinline__ void phase_barrier() {
  asm volatile("s_waitcnt lgkmcnt(0)" ::: "memory");
  __builtin_amdgcn_s_barrier();
  asm volatile("" ::: "memory");
}
__device__ __forceinline__ void vm_drain() {
  asm volatile("s_waitcnt vmcnt(0)" ::: "memory");
}
// direct global->LDS DMA, 16B per lane. LDS dest: wave-uniform base + lane*16.
__device__ __forceinline__ void gload_lds16(const u16* g, u16* l) {
  __builtin_amdgcn_global_load_lds((const __attribute__((address_space(1))) void*)g,
                                   (__attribute__((address_space(3))) void*)l, 16, 0, 0);
}
// bijective chunked XCD swizzle (m204)
__device__ __forceinline__ int xcd_swizzle(int lid, int nwg) {
  int q = nwg >> 3, r = nwg & 7, x = lid & 7, s = lid >> 3;
  return (x < r ? x * (q + 1) : r * (q + 1) + (x - r) * q) + s;
}

// ---------------- transpose f32 (R,C) -> bf16 (C,R) ----------------
__global__ __launch_bounds__(256) void transpose_f2b(const float* __restrict__ in,
                                                     u16* __restrict__ out, int R, int C) {
  __shared__ __align__(16) u16 tile[32][33];
  int tx = threadIdx.x & 31, ty = threadIdx.x >> 5;
  int c0 = blockIdx.x * 32, r0 = blockIdx.y * 32;
#pragma unroll
  for (int i = 0; i < 4; ++i) {
    int r = r0 + ty + i * 8, c = c0 + tx;
    if (r < R && c < C) tile[ty + i * 8][tx] = f2b(in[(size_t)r * C + c]);
  }
  __syncthreads();
#pragma unroll
  for (int i = 0; i < 4; ++i) {
    int oc = c0 + ty + i * 8, orr = r0 + tx;
    if (oc < C && orr < R) out[(size_t)oc * R + orr] = tile[tx][ty + i * 8];
  }
}

// ------- WgT[n,k]=g[k]*WT[n,k]; u[n]=sum g*W; w[n]=sum b*W -------
__global__ __launch_bounds__(256) void prep_wg(const u16* __restrict__ WT, const float* __restrict__ g,
                                               const float* __restrict__ b, u16* __restrict__ WgT,
                                               float* __restrict__ ucol, float* __restrict__ wcol,
                                               int K) {
  int n = blockIdx.x * 4 + (threadIdx.x >> 6);
  int lane = threadIdx.x & 63;
  const u16* src = WT + (size_t)n * K;
  u16* dst = WgT + (size_t)n * K;
  float su = 0.f, sw = 0.f;
  for (int k = lane; k < K; k += 64) {
    float wc = b2f(src[k]);
    float wg = g[k] * wc;
    dst[k] = f2b(wg);
    su += wg;
    sw += b[k] * wc;
  }
#pragma unroll
  for (int off = 32; off >= 1; off >>= 1) {
    su += __shfl_xor(su, off, 64);
    sw += __shfl_xor(sw, off, 64);
  }
  if (lane == 0) { ucol[n] = su; wcol[n] = sw; }
}

// ------- hs f32 -> bf16 + per-row LN stats (for folded q GEMM) -------
__global__ __launch_bounds__(256) void hs_prep(const float* __restrict__ hs, u16* __restrict__ out,
                                               float* __restrict__ rstdg, float* __restrict__ mrstdg) {
  int row = blockIdx.x * 4 + (threadIdx.x >> 6);
  int lane = threadIdx.x & 63;
  const float* x = hs + (size_t)row * 768;
  float v[12];
#pragma unroll
  for (int it = 0; it < 3; ++it) {
    int c = (lane + it * 64) * 4;
    f32x4 d = *(const f32x4*)(x + c);
    v[it * 4 + 0] = d[0]; v[it * 4 + 1] = d[1]; v[it * 4 + 2] = d[2]; v[it * 4 + 3] = d[3];
  }
  float s = 0.f, s2 = 0.f;
#pragma unroll
  for (int i = 0; i < 12; ++i) { s += v[i]; s2 += v[i] * v[i]; }
#pragma unroll
  for (int off = 32; off >= 1; off >>= 1) {
    s += __shfl_xor(s, off, 64);
    s2 += __shfl_xor(s2, off, 64);
  }
  float inv_n = 1.0f / 768.f;
  float mean = s * inv_n;
  float var = fmaxf(s2 * inv_n - mean * mean, 0.f);
  float rstd = rsqrtf(var + 1e-5f);
  if (lane == 0) { rstdg[row] = rstd; mrstdg[row] = mean * rstd; }
#pragma unroll
  for (int it = 0; it < 3; ++it) {
    int c = (lane + it * 64) * 4;
    uint2 po;
    po.x = (uint32_t)f2b(v[it * 4 + 0]) | ((uint32_t)f2b(v[it * 4 + 1]) << 16);
    po.y = (uint32_t)f2b(v[it * 4 + 2]) | ((uint32_t)f2b(v[it * 4 + 3]) << 16);
    *(uint2*)(out + (size_t)row * 768 + c) = po;
  }
}

// --- h = hs + sigmoid(gate)*LN(ao): outputs f32 h, bf16 h, per-row LN stats of h ---
__global__ __launch_bounds__(256) void ln_res(const u16* __restrict__ ao, const float* __restrict__ g,
                                              const float* __restrict__ bta,
                                              const float* __restrict__ hs,
                                              const float* __restrict__ gatep,
                                              float* __restrict__ hf, u16* __restrict__ hb,
                                              float* __restrict__ rstdg, float* __restrict__ mrstdg) {
  int row = blockIdx.x * 4 + (threadIdx.x >> 6);
  int lane = threadIdx.x & 63;
  const u16* xb = ao + (size_t)row * 768;
  float v[12];
#pragma unroll
  for (int it = 0; it < 3; ++it) {
    int c = (lane + it * 64) * 4;
    uint2 d = *(const uint2*)(xb + c);
    v[it * 4 + 0] = b2f(d.x & 0xffff); v[it * 4 + 1] = b2f(d.x >> 16);
    v[it * 4 + 2] = b2f(d.y & 0xffff); v[it * 4 + 3] = b2f(d.y >> 16);
  }
  float s = 0.f, s2 = 0.f;
#pragma unroll
  for (int i = 0; i < 12; ++i) { s += v[i]; s2 += v[i] * v[i]; }
#pragma unroll
  for (int off = 32; off >= 1; off >>= 1) {
    s += __shfl_xor(s, off, 64);
    s2 += __shfl_xor(s2, off, 64);
  }
  float inv_n = 1.0f / 768.f;
  float mean = s * inv_n;
  float var = fmaxf(s2 * inv_n - mean * mean, 0.f);
  float rstd = rsqrtf(var + 1e-5f);
  float gate = 1.f / (1.f + __expf(-gatep[0]));
  float hsum = 0.f, hsum2 = 0.f;
  float o[12];
#pragma unroll
  for (int it = 0; it < 3; ++it) {
    int c = (lane + it * 64) * 4;
    const float* rr = hs + (size_t)row * 768 + c;
#pragma unroll
    for (int i = 0; i < 4; ++i) {
      float hv = rr[i] + gate * ((v[it * 4 + i] - mean) * rstd * g[c + i] + bta[c + i]);
      o[it * 4 + i] = hv;
      hsum += hv; hsum2 += hv * hv;
    }
    *(f32x4*)(hf + (size_t)row * 768 + c) = (f32x4){o[it * 4 + 0], o[it * 4 + 1], o[it * 4 + 2], o[it * 4 + 3]};
    uint2 po;
    po.x = (uint32_t)f2b(o[it * 4 + 0]) | ((uint32_t)f2b(o[it * 4 + 1]) << 16);
    po.y = (uint32_t)f2b(o[it * 4 + 2]) | ((uint32_t)f2b(o[it * 4 + 3]) << 16);
    *(uint2*)(hb + (size_t)row * 768 + c) = po;
  }
#pragma unroll
  for (int off = 32; off >= 1; off >>= 1) {
    hsum += __shfl_xor(hsum, off, 64);
    hsum2 += __shfl_xor(hsum2, off, 64);
  }
  float hm = hsum * inv_n;
  float hvar = fmaxf(hsum2 * inv_n - hm * hm, 0.f);
  float hrstd = rsqrtf(hvar + 1e-5f);
  if (lane == 0) { rstdg[row] = hrstd; mrstdg[row] = hm * hrstd; }
}

// ---------------- MFMA GEMM: C = A(MxK)*BT(NxK)^T, 128x128 tile, BK=32 ----------------
// T3 2-phase: STAGE(next) || ds_read+MFMA(cur); one vmcnt(0)+barrier per step.
// bf16 operands staged via global_load_lds (linear dest, pre-swizzled source);
// f32 operands reg-staged with swizzled ds_write. XOR swizzle: slot c holds
// global chunk c^(row&3); read addr = row*64B + ((quad^(row&3))*16B.
// AMODE/BMODE: 0 bf16-DMA | 1 f32-reg. EPI: 0 none | 1 +bias |
// 3 LNfold(precomp rstdg/mrstdg)+bias | 4 LNfold(in-GEMM stats, AMODE=1)+bias |
// 5 LNfold(precomp)+bias+gelu. VTOUT: kv-only split K/V epilogue.
template <int SPLITK, int AMODE, int BMODE, int EPI, bool OUTF32, bool VTOUT>
__device__ __forceinline__ void gemm_body(const void* __restrict__ Av, const void* __restrict__ Bv,
                                          const float* __restrict__ bias,
                                          const float* __restrict__ rstdg,
                                          const float* __restrict__ mrstdg,
                                          const float* __restrict__ ucol,
                                          const float* __restrict__ wcol,
                                          void* __restrict__ Cv, u16* __restrict__ VTout,
                                          int M, int N, int K) {
  __shared__ __align__(16) u16 aT[2][128 * 32];
  __shared__ __align__(16) u16 bT[2][128 * 32];
  __shared__ float rstd_s[EPI == 4 ? 128 : 1];
  __shared__ float mrstd_s[EPI == 4 ? 128 : 1];
  __shared__ __align__(16) u16 vtile[VTOUT ? 64 * 136 : 1];

  int gx = gridDim.x, gy = gridDim.y;
  int nwg = gx * gy * (int)gridDim.z;
  int lid = ((int)blockIdx.z * gy + (int)blockIdx.y) * gx + (int)blockIdx.x;
  int wid = xcd_swizzle(lid, nwg);
  int bz = wid / (gx * gy);
  int rem = wid - bz * (gx * gy);
  int bx = rem / gy;
  int by = rem - bx * gy;

  int t = threadIdx.x, lane = t & 63, wave = t >> 6;
  int quad = lane >> 4, lcol = lane & 15;
  int wm = (wave >> 1) * 64, wn = (wave & 1) * 64;
  const u16* Ab = (const u16*)Av;
  const float* Af = (const float*)Av;
  const u16* Bb = (const u16*)Bv;
  const float* Bf = (const float*)Bv;
  const int kchunk = (SPLITK > 1) ? K / SPLITK : K;
  const int kstart = (SPLITK > 1) ? bz * kchunk : 0;
  // reg-stage mapping: row rr, 16 cols at rc*16
  int rr = t >> 1, rc = t & 1;
  float sa = 0.f, sa2 = 0.f;
  f32x4 acc[4][4];
#pragma unroll
  for (int i = 0; i < 4; ++i)
#pragma unroll
    for (int j = 0; j < 4; ++j) acc[i][j] = (f32x4){0.f, 0.f, 0.f, 0.f};

  f32x4 araw[4], braw[4];

  auto dmaA = [&](int buf, int k0) {
#pragma unroll
    for (int s2 = 0; s2 < 2; ++s2) {
      int row = (wave * 2 + s2) * 16 + (lane >> 2);
      int ch = (lane & 3) ^ (row & 3);
      gload_lds16(Ab + (size_t)(bx * 128 + row) * K + kstart + k0 + ch * 8,
                  &aT[buf][(wave * 2 + s2) * 512]);
    }
  };
  auto dmaB = [&](int buf, int k0) {
#pragma unroll
    for (int s2 = 0; s2 < 2; ++s2) {
      int row = (wave * 2 + s2) * 16 + (lane >> 2);
      int ch = (lane & 3) ^ (row & 3);
      gload_lds16(Bb + (size_t)(by * 128 + row) * K + kstart + k0 + ch * 8,
                  &bT[buf][(wave * 2 + s2) * 512]);
    }
  };
  auto regloadA = [&](int k0) {
    const f32x4* p = (const f32x4*)&Af[(size_t)(bx * 128 + rr) * K + kstart + k0 + rc * 16];
#pragma unroll
    for (int i = 0; i < 4; ++i) araw[i] = p[i];
  };
  auto regstoreA = [&](int buf) {
    if (EPI == 4) {
#pragma unroll
      for (int i = 0; i < 4; ++i)
#pragma unroll
        for (int j = 0; j < 4; ++j) { sa += araw[i][j]; sa2 += araw[i][j] * araw[i][j]; }
    }
    uint4 c0 = pack8(araw[0], araw[1]), c1 = pack8(araw[2], araw[3]);
    *(uint4*)&aT[buf][rr * 32 + (((rc * 2 + 0) ^ (rr & 3)) << 3)] = c0;
    *(uint4*)&aT[buf][rr * 32 + (((rc * 2 + 1) ^ (rr & 3)) << 3)] = c1;
  };
  auto regloadB = [&](int k0) {
    const f32x4* p = (const f32x4*)&Bf[(size_t)(by * 128 + rr) * K + kstart + k0 + rc * 16];
#pragma unroll
    for (int i = 0; i < 4; ++i) braw[i] = p[i];
  };
  auto regstoreB = [&](int buf) {
    uint4 c0 = pack8(braw[0], braw[1]), c1 = pack8(braw[2], braw[3]);
    *(uint4*)&bT[buf][rr * 32 + (((rc * 2 + 0) ^ (rr & 3)) << 3)] = c0;
    *(uint4*)&bT[buf][rr * 32 + (((rc * 2 + 1) ^ (rr & 3)) << 3)] = c1;
  };
  auto stage_load = [&](int buf, int k0) {
    if (AMODE == 1) regloadA(k0); else dmaA(buf, k0);
    if (BMODE == 1) regloadB(k0); else dmaB(buf, k0);
  };
  auto stage_store = [&](int buf) {
    if (AMODE == 1) regstoreA(buf);
    if (BMODE == 1) regstoreB(buf);
  };
  auto compute = [&](int buf) {
    bf16x8 af[4], bfr[4];
#pragma unroll
    for (int mt = 0; mt < 4; ++mt) {
      int r = wm + mt * 16 + lcol;
      af[mt] = *(const bf16x8*)&aT[buf][r * 32 + (((quad ^ (r & 3))) << 3)];
    }
#pragma unroll
    for (int nt = 0; nt < 4; ++nt) {
      int r = wn + nt * 16 + lcol;
      bfr[nt] = *(const bf16x8*)&bT[buf][r * 32 + (((quad ^ (r & 3))) << 3)];
    }
#pragma unroll
    for (int mt = 0; mt < 4; ++mt)
#pragma unroll
      for (int nt = 0; nt < 4; ++nt)
        acc[mt][nt] = __builtin_amdgcn_mfma_f32_16x16x32_bf16(af[mt], bfr[nt], acc[mt][nt], 0, 0, 0);
  };

  const int nk = kchunk >> 5;
  stage_load(0, 0);
  stage_store(0);
  vm_drain();
  phase_barrier();
  int cur = 0;
  for (int kt = 0; kt < nk; ++kt) {
    bool more = kt + 1 < nk;
    if (more) stage_load(cur ^ 1, (kt + 1) << 5);   // issue early (DMA fire-and-forget / reg loads)
    compute(cur);                                   // hide latency under ds_read + MFMA
    if (more) stage_store(cur ^ 1);                 // reg paths: pack + ds_write late
    vm_drain();
    phase_barrier();
    cur ^= 1;
  }

  if (EPI == 4) {
    float s = sa, s2 = sa2;
    s += __shfl_xor(s, 1, 64);
    s2 += __shfl_xor(s2, 1, 64);
    if ((t & 1) == 0) {
      float inv_n = 1.0f / (float)K;
      float mean = s * inv_n;
      float var = fmaxf(s2 * inv_n - mean * mean, 0.f);
      float rstd = rsqrtf(var + 1e-5f);
      rstd_s[rr] = rstd;
      mrstd_s[rr] = mean * rstd;
    }
    __syncthreads();
  }

  if (VTOUT) {
    // kv: cols 0..63 -> kb[M][64]; cols 64..127 -> LDS transpose -> VT[b][d][j]
    u16* kb = (u16*)Cv;
#pragma unroll
    for (int mt = 0; mt < 4; ++mt) {
#pragma unroll
      for (int nt = 0; nt < 4; ++nt) {
#pragma unroll
        for (int r = 0; r < 4; ++r) {
          int lrow = wm + mt * 16 + quad * 4 + r;
          int row = bx * 128 + lrow;
          int col = wn + nt * 16 + lcol;
          float v = rstd_s[lrow] * acc[mt][nt][r] - mrstd_s[lrow] * ucol[col] + wcol[col] + bias[col];
          u16 hv = f2b(v);
          if (wn == 0) kb[(size_t)row * 64 + col] = hv;
          else vtile[(col - 64) * 136 + lrow] = hv;
        }
      }
    }
    __syncthreads();
    int dd = t >> 2, js = (t & 3) * 32;
    int bg = bx >> 5, j0g = (bx & 31) * 128;
    u16* dst = VTout + ((size_t)bg * 64 + dd) * 4096 + j0g + js;
#pragma unroll
    for (int i = 0; i < 4; ++i)
      *(uint4*)(dst + i * 8) = *(const uint4*)&vtile[dd * 136 + js + i * 8];
    return;
  }

  u16* Cb = (u16*)Cv;
  float* Cf = (float*)Cv;
  if (SPLITK > 1) Cf += (size_t)bz * (size_t)M * (size_t)N;
#pragma unroll
  for (int mt = 0; mt < 4; ++mt) {
#pragma unroll
    for (int nt = 0; nt < 4; ++nt) {
#pragma unroll
      for (int r = 0; r < 4; ++r) {
        int lrow = wm + mt * 16 + quad * 4 + r;
        int row = bx * 128 + lrow;
        int col = by * 128 + wn + nt * 16 + lcol;
        float v = acc[mt][nt][r];
        if (EPI == 1) v += bias[col];
        if (EPI == 3 || EPI == 5)
          v = rstdg[row] * v - mrstdg[row] * ucol[col] + wcol[col] + bias[col];
        if (EPI == 5) v = 0.5f * v * (1.f + erff(v * 0.70710678118f));
        size_t idx = (size_t)row * N + col;
        if (OUTF32) Cf[idx] = v; else Cb[idx] = f2b(v);
      }
    }
  }
}

// distinct names per call site (rocprof attribution)
#define GEMM_ARGS const void* Av, const void* Bv, const float* bias, const float* rstdg, \
                  const float* mrstdg, const float* ucol, const float* wcol, void* Cv,   \
                  u16* VTout, int M, int N, int K
__global__ __launch_bounds__(256) void gemm_wc(GEMM_ARGS) {
  gemm_body<1, 0, 1, 0, false, false>(Av, Bv, bias, rstdg, mrstdg, ucol, wcol, Cv, VTout, M, N, K);
}
__global__ __launch_bounds__(256) void gemm_kv(GEMM_ARGS) {
  gemm_body<1, 1, 0, 4, false, true>(Av, Bv, bias, rstdg, mrstdg, ucol, wcol, Cv, VTout, M, N, K);
}
__global__ __launch_bounds__(256) void gemm_q(GEMM_ARGS) {
  gemm_body<1, 0, 0, 3, false, false>(Av, Bv, bias, rstdg, mrstdg, ucol, wcol, Cv, VTout, M, N, K);
}
__global__ __launch_bounds__(256) void gemm_o(GEMM_ARGS) {
  gemm_body<1, 0, 0, 1, false, false>(Av, Bv, bias, rstdg, mrstdg, ucol, wcol, Cv, VTout, M, N, K);
}
__global__ __launch_bounds__(256) void gemm_w1(GEMM_ARGS) {
  gemm_body<1, 0, 0, 5, false, false>(Av, Bv, bias, rstdg, mrstdg, ucol, wcol, Cv, VTout, M, N, K);
}
__global__ __launch_bounds__(256) void gemm_w2(GEMM_ARGS) {
  gemm_body<2, 0, 0, 0, true, false>(Av, Bv, bias, rstdg, mrstdg, ucol, wcol, Cv, VTout, M, N, K);
}

// ---------------- split-K merge for W2: out = p0 + p1 + h + b2 ----------------
__global__ __launch_bounds__(256) void w2_merge(const float* __restrict__ part,
                                                const float* __restrict__ hf,
                                                const float* __restrict__ b2,
                                                float* __restrict__ out) {
  int idx = blockIdx.x * 256 + threadIdx.x;
  f32x4 p0 = ((const f32x4*)part)[idx];
  f32x4 p1 = ((const f32x4*)part)[idx + 393216];
  f32x4 h = ((const f32x4*)hf)[idx];
  f32x4 bb = ((const f32x4*)b2)[idx % 192];
  f32x4 o;
#pragma unroll
  for (int i = 0; i < 4; ++i) o[i] = p0[i] + p1[i] + h[i] + bb[i];
  ((f32x4*)out)[idx] = o;
}

// ---------------- flash attention, MQA (NKV=1), HD=64, no-max softmax, j-split=2 ----------------
__global__ __launch_bounds__(256) void attn_kernel(const u16* __restrict__ qbuf,
                                                   const u16* __restrict__ kb,
                                                   const u16* __restrict__ VT,
                                                   float* __restrict__ Opart,
                                                   float* __restrict__ lpart) {
  __shared__ __align__(16) u16 k_lds[64 * 72];
  __shared__ __align__(16) u16 vt_lds[64 * 72];
  __shared__ __align__(16) u16 p_lds[4 * 16 * 72];
  int lid = ((int)blockIdx.z * 12 + (int)blockIdx.y) * 4 + (int)blockIdx.x;
  int wid = (lid & 7) * 96 + (lid >> 3);
  int bi = wid & 3;
  int h = (wid >> 2) % 12;
  int z = wid / 48;
  int b = z >> 1, s = z & 1;
  int t = threadIdx.x;
  int wave = t >> 6, lane = t & 63, quad = lane >> 4, lcol = lane & 15;
  int i0 = bi * 64 + wave * 16;
  const u16* qrow = qbuf + ((size_t)(b * 256 + i0 + lcol) * 768 + h * 64 + quad * 8);
  bf16x8 qf0 = *(const bf16x8*)qrow;
  bf16x8 qf1 = *(const bf16x8*)(qrow + 32);
  float l_r[4] = {0.f, 0.f, 0.f, 0.f};
  f32x4 oacc[4];
#pragma unroll
  for (int nt = 0; nt < 4; ++nt) oacc[nt] = (f32x4){0.f, 0.f, 0.f, 0.f};
  int sr = t >> 2, sc = (t & 3) * 16;
  const u16* kbase = kb + (size_t)b * 4096 * 64;
  const u16* vtbase = VT + (size_t)b * 64 * 4096;
  u16* pw = &p_lds[wave * 16 * 72];

  for (int jt = 0; jt < 32; ++jt) {
    int j0 = s * 2048 + jt * 64;
    const u16* krow = kbase + (size_t)(j0 + sr) * 64 + sc;
    *(uint4*)&k_lds[sr * 72 + sc] = *(const uint4*)(krow);
    *(uint4*)&k_lds[sr * 72 + sc + 8] = *(const uint4*)(krow + 8);
    const u16* vrow = vtbase + (size_t)sr * 4096 + j0 + sc;
    *(uint4*)&vt_lds[sr * 72 + sc] = *(const uint4*)(vrow);
    *(uint4*)&vt_lds[sr * 72 + sc + 8] = *(const uint4*)(vrow + 8);
    __syncthreads();

    f32x4 sc4[4];
#pragma unroll
    for (int nt = 0; nt < 4; ++nt) sc4[nt] = (f32x4){0.f, 0.f, 0.f, 0.f};
#pragma unroll
    for (int nt = 0; nt < 4; ++nt) {
      bf16x8 kb0 = *(const bf16x8*)&k_lds[(nt * 16 + lcol) * 72 + quad * 8];
      bf16x8 kb1 = *(const bf16x8*)&k_lds[(nt * 16 + lcol) * 72 + 32 + quad * 8];
      sc4[nt] = __builtin_amdgcn_mfma_f32_16x16x32_bf16(qf0, kb0, sc4[nt], 0, 0, 0);
      sc4[nt] = __builtin_amdgcn_mfma_f32_16x16x32_bf16(qf1, kb1, sc4[nt], 0, 0, 0);
    }
#pragma unroll
    for (int r = 0; r < 4; ++r) {
      float rsum = 0.f;
#pragma unroll
      for (int nt = 0; nt < 4; ++nt) {
        float p = __expf(sc4[nt][r] * 0.125f);
        sc4[nt][r] = p;
        rsum += p;
      }
      rsum += __shfl_xor(rsum, 1, 64);
      rsum += __shfl_xor(rsum, 2, 64);
      rsum += __shfl_xor(rsum, 4, 64);
      rsum += __shfl_xor(rsum, 8, 64);
      l_r[r] += rsum;
#pragma unroll
      for (int nt = 0; nt < 4; ++nt) pw[(quad * 4 + r) * 72 + nt * 16 + lcol] = f2b(sc4[nt][r]);
    }
#pragma unroll
    for (int ks = 0; ks < 2; ++ks) {
      bf16x8 pa = *(const bf16x8*)&pw[lcol * 72 + ks * 32 + quad * 8];
#pragma unroll
      for (int nt = 0; nt < 4; ++nt) {
        bf16x8 vb = *(const bf16x8*)&vt_lds[(nt * 16 + lcol) * 72 + ks * 32 + quad * 8];
        oacc[nt] = __builtin_amdgcn_mfma_f32_16x16x32_bf16(pa, vb, oacc[nt], 0, 0, 0);
      }
    }
    __syncthreads();
  }
  size_t base = ((size_t)z * 12 + h) * 256;
#pragma unroll
  for (int r = 0; r < 4; ++r) {
    int row = bi * 64 + wave * 16 + quad * 4 + r;
#pragma unroll
    for (int nt = 0; nt < 4; ++nt)
      Opart[(base + row) * 64 + nt * 16 + lcol] = oacc[nt][r];
    if (lcol == 0) lpart[base + row] = l_r[r];
  }
}

// ---------------- merge j-split partials -> attn_o bf16 ----------------
__global__ __launch_bounds__(256) void attn_merge(const float* __restrict__ Opart,
                                                  const float* __restrict__ lpart,
                                                  u16* __restrict__ attn_o) {
  int row = blockIdx.x;
  int col = blockIdx.y * 256 + threadIdx.x;
  int b = row >> 8, i = row & 255, h = col >> 6, d = col & 63;
  size_t i0 = (((size_t)(b * 2 + 0) * 12 + h) * 256 + i);
  size_t i1 = (((size_t)(b * 2 + 1) * 12 + h) * 256 + i);
  float o = Opart[i0 * 64 + d] + Opart[i1 * 64 + d];
  float l = lpart[i0] + lpart[i1];
  attn_o[(size_t)row * 768 + col] = f2b(o / l);
}

// ---------------- launch ----------------
extern "C" void kernel_launch(void* const* d_in, const int* in_sizes, int n_in, void* d_out,
                              int out_size, void* d_ws, size_t ws_size, hipStream_t stream) {
  (void)in_sizes; (void)n_in; (void)out_size; (void)ws_size;
  const float* hs = (const float*)d_in[0];
  const float* imgf = (const float*)d_in[1];
  const float* ln_img_g = (const float*)d_in[2];
  const float* ln_img_b = (const float*)d_in[3];
  const float* W_bottle = (const float*)d_in[4];
  const float* ln_h_g = (const float*)d_in[5];
  const float* ln_h_b = (const float*)d_in[6];
  const float* Wq = (const float*)d_in[7];
  const float* bq = (const float*)d_in[8];
  const float* Wkv = (const float*)d_in[9];
  const float* bkv = (const float*)d_in[10];
  const float* Wo = (const float*)d_in[11];
  const float* bo = (const float*)d_in[12];
  const float* ln_ao_g = (const float*)d_in[13];
  const float* ln_ao_b = (const float*)d_in[14];
  const float* gatep = (const float*)d_in[15];
  const float* ln_f_g = (const float*)d_in[16];
  const float* ln_f_b = (const float*)d_in[17];
  const float* W1 = (const float*)d_in[18];
  const float* b1 = (const float*)d_in[19];
  const float* W2 = (const float*)d_in[20];
  const float* b2 = (const float*)d_in[21];

  char* sc = (char*)d_ws;
  auto alloc = [&](size_t bytes) {
    char* p = sc;
    sc += (bytes + 63) & ~(size_t)63;
    return p;
  };
  u16* WTq = (u16*)alloc(768 * 768 * 2);
  u16* WTo = (u16*)alloc(768 * 768 * 2);
  u16* WT1 = (u16*)alloc(3072 * 768 * 2);
  u16* WT2 = (u16*)alloc(768 * 3072 * 2);
  u16* WkvT = (u16*)alloc(128 * 768 * 2);
  u16* WcT = (u16*)alloc(128 * 1024 * 2);
  u16* WgT = (u16*)alloc(128 * 1024 * 2);
  u16* WqgT = (u16*)alloc(768 * 768 * 2);
  u16* W1gT = (u16*)alloc(3072 * 768 * 2);
  float* ucol = (float*)alloc(128 * 4);
  float* wcol = (float*)alloc(128 * 4);
  float* uq = (float*)alloc(768 * 4);
  float* wq = (float*)alloc(768 * 4);
  float* u1 = (float*)alloc(3072 * 4);
  float* w1c = (float*)alloc(3072 * 4);
  float* rstdq = (float*)alloc(2048 * 4);
  float* mrstdq = (float*)alloc(2048 * 4);
  float* rstdh = (float*)alloc(2048 * 4);
  float* mrstdh = (float*)alloc(2048 * 4);
  u16* hs16 = (u16*)alloc(2048 * 768 * 2);
  u16* kb = (u16*)alloc((size_t)32768 * 64 * 2);
  u16* VT = (u16*)alloc((size_t)8 * 64 * 4096 * 2);
  u16* qb = (u16*)alloc(2048 * 768 * 2);
  u16* attn_o = (u16*)alloc(2048 * 768 * 2);
  u16* ao = (u16*)alloc(2048 * 768 * 2);
  u16* hbuf = (u16*)alloc(2048 * 768 * 2);
  float* hf32 = (float*)alloc(2048 * 768 * 4);
  u16* actb = (u16*)alloc((size_t)2048 * 3072 * 2);
  float* Opart = (float*)alloc((size_t)16 * 12 * 256 * 64 * 4);  // also W2 split-K partials
  float* lpart = (float*)alloc((size_t)16 * 12 * 256 * 4);

  // weight transposes (f32 -> bf16, (N,K) layout)
  transpose_f2b<<<dim3(24, 24), 256, 0, stream>>>(Wq, WTq, 768, 768);
  transpose_f2b<<<dim3(24, 24), 256, 0, stream>>>(Wo, WTo, 768, 768);
  transpose_f2b<<<dim3(96, 24), 256, 0, stream>>>(W1, WT1, 768, 3072);
  transpose_f2b<<<dim3(24, 96), 256, 0, stream>>>(W2, WT2, 3072, 768);
  transpose_f2b<<<dim3(4, 24), 256, 0, stream>>>(Wkv, WkvT, 768, 128);

  // WcT[n,kimg] = sum_j WkvT[n,j] * W_bottle[kimg,j]  (B f32 reg-staged)
  gemm_wc<<<dim3(1, 8), 256, 0, stream>>>(WkvT, W_bottle, nullptr, nullptr, nullptr, nullptr,
                                          nullptr, WcT, nullptr, 128, 1024, 768);
  // LN-fold weight preps
  prep_wg<<<32, 256, 0, stream>>>(WcT, ln_img_g, ln_img_b, WgT, ucol, wcol, 1024);
  prep_wg<<<192, 256, 0, stream>>>(WTq, ln_h_g, ln_h_b, WqgT, uq, wq, 768);
  prep_wg<<<768, 256, 0, stream>>>(WT1, ln_f_g, ln_f_b, W1gT, u1, w1c, 768);
  // hs -> bf16 + LN stats (for folded q)
  hs_prep<<<512, 256, 0, stream>>>(hs, hs16, rstdq, mrstdq);
  // kv (fused img-LN, in-GEMM stats from f32 A) -> kb + VT
  gemm_kv<<<dim3(256, 1), 256, 0, stream>>>(imgf, WgT, bkv, nullptr, nullptr, ucol, wcol,
                                            kb, VT, 32768, 128, 1024);
  // q = LN(hs) @ Wq + bq  (folded, precomputed stats)
  gemm_q<<<dim3(16, 6), 256, 0, stream>>>(hs16, WqgT, bq, rstdq, mrstdq, uq, wq,
                                          qb, nullptr, 2048, 768, 768);
  // attention (j-split=2) + merge
  attn_kernel<<<dim3(4, 12, 16), 256, 0, stream>>>(qb, kb, VT, Opart, lpart);
  attn_merge<<<dim3(2048, 3), 256, 0, stream>>>(Opart, lpart, attn_o);
  // out proj
  gemm_o<<<dim3(16, 6), 256, 0, stream>>>(attn_o, WTo, bo, nullptr, nullptr, nullptr, nullptr,
                                          ao, nullptr, 2048, 768, 768);
  // h = hs + sigmoid(gate)*LN(ao): f32 + bf16 + h-stats
  ln_res<<<512, 256, 0, stream>>>(ao, ln_ao_g, ln_ao_b, hs, gatep, hf32, hbuf, rstdh, mrstdh);
  // act = gelu(LN(h) @ W1 + b1)  (folded, precomputed stats)
  gemm_w1<<<dim3(16, 24), 256, 0, stream>>>(hbuf, W1gT, b1, rstdh, mrstdh, u1, w1c,
                                            actb, nullptr, 2048, 3072, 768);
  // W2 split-K=2 partials into Opart, then merge with h + b2
  gemm_w2<<<dim3(16, 6, 2), 256, 0, stream>>>(actb, WT2, nullptr, nullptr, nullptr, nullptr, nullptr,
                                              Opart, nullptr, 2048, 768, 3072);
  w2_merge<<<1536, 256, 0, stream>>>(Opart, hf32, b2, (float*)d_out);
}

// Round 6
// 519.085 us; speedup vs baseline: 1.2772x; 1.0327x over previous
//
#include <hip/hip_runtime.h>
#include <cstdint>

typedef unsigned short u16;
typedef __bf16 bf16_t;
typedef bf16_t bf16x8 __attribute__((ext_vector_type(8)));
typedef float f32x4 __attribute__((ext_vector_type(4)));

__device__ __forceinline__ float b2f(u16 v) {
  union { uint32_t u; float f; } c; c.u = ((uint32_t)v) << 16; return c.f;
}
__device__ __forceinline__ u16 f2b(float f) {
  union { float f; uint32_t u; } c; c.f = f;
  uint32_t lsb = (c.u >> 16) & 1u;
  return (u16)((c.u + 0x7fffu + lsb) >> 16);
}
__device__ __forceinline__ uint4 pack8(f32x4 a, f32x4 b) {
  union { uint4 v; u16 s[8]; } r;
  r.s[0] = f2b(a[0]); r.s[1] = f2b(a[1]); r.s[2] = f2b(a[2]); r.s[3] = f2b(a[3]);
  r.s[4] = f2b(b[0]); r.s[5] = f2b(b[1]); r.s[6] = f2b(b[2]); r.s[7] = f2b(b[3]);
  return r.v;
}
// packed f32x2 -> bf16x2 (RNE), single instruction (no builtin on gfx950)
__device__ __forceinline__ uint32_t cvt_pk_bf16(float lo, float hi) {
  uint32_t r;
  asm("v_cvt_pk_bf16_f32 %0, %1, %2" : "=v"(r) : "v"(lo), "v"(hi));
  return r;
}
// raw barrier: lgkm drain + s_barrier (no implicit vmcnt drain)
__device__ __forceinline__ void phase_barrier() {
  asm volatile("s_waitcnt lgkmcnt(0)" ::: "memory");
  __builtin_amdgcn_s_barrier();
  asm volatile("" ::: "memory");
}
__device__ __forceinline__ void vm_drain() {
  asm volatile("s_waitcnt vmcnt(0)" ::: "memory");
}
// direct global->LDS DMA, 16B per lane. LDS dest: wave-uniform base + lane*16.
__device__ __forceinline__ void gload_lds16(const u16* g, u16* l) {
  __builtin_amdgcn_global_load_lds((const __attribute__((address_space(1))) void*)g,
                                   (__attribute__((address_space(3))) void*)l, 16, 0, 0);
}
// bijective chunked XCD swizzle (m204)
__device__ __forceinline__ int xcd_swizzle(int lid, int nwg) {
  int q = nwg >> 3, r = nwg & 7, x = lid & 7, s = lid >> 3;
  return (x < r ? x * (q + 1) : r * (q + 1) + (x - r) * q) + s;
}

// ---------------- transpose f32 (R,C) -> bf16 (C,R) ----------------
__global__ __launch_bounds__(256) void transpose_f2b(const float* __restrict__ in,
                                                     u16* __restrict__ out, int R, int C) {
  __shared__ __align__(16) u16 tile[32][33];
  int tx = threadIdx.x & 31, ty = threadIdx.x >> 5;
  int c0 = blockIdx.x * 32, r0 = blockIdx.y * 32;
#pragma unroll
  for (int i = 0; i < 4; ++i) {
    int r = r0 + ty + i * 8, c = c0 + tx;
    if (r < R && c < C) tile[ty + i * 8][tx] = f2b(in[(size_t)r * C + c]);
  }
  __syncthreads();
#pragma unroll
  for (int i = 0; i < 4; ++i) {
    int oc = c0 + ty + i * 8, orr = r0 + tx;
    if (oc < C && orr < R) out[(size_t)oc * R + orr] = tile[tx][ty + i * 8];
  }
}

// ------- WgT[n,k]=g[k]*WT[n,k]; u[n]=sum g*W; w[n]=sum b*W -------
__global__ __launch_bounds__(256) void prep_wg(const u16* __restrict__ WT, const float* __restrict__ g,
                                               const float* __restrict__ b, u16* __restrict__ WgT,
                                               float* __restrict__ ucol, float* __restrict__ wcol,
                                               int K) {
  int n = blockIdx.x * 4 + (threadIdx.x >> 6);
  int lane = threadIdx.x & 63;
  const u16* src = WT + (size_t)n * K;
  u16* dst = WgT + (size_t)n * K;
  float su = 0.f, sw = 0.f;
  for (int k = lane; k < K; k += 64) {
    float wc = b2f(src[k]);
    float wg = g[k] * wc;
    dst[k] = f2b(wg);
    su += wg;
    sw += b[k] * wc;
  }
#pragma unroll
  for (int off = 32; off >= 1; off >>= 1) {
    su += __shfl_xor(su, off, 64);
    sw += __shfl_xor(sw, off, 64);
  }
  if (lane == 0) { ucol[n] = su; wcol[n] = sw; }
}

// ------- hs f32 -> bf16 + per-row LN stats (for folded q GEMM) -------
__global__ __launch_bounds__(256) void hs_prep(const float* __restrict__ hs, u16* __restrict__ out,
                                               float* __restrict__ rstdg, float* __restrict__ mrstdg) {
  int row = blockIdx.x * 4 + (threadIdx.x >> 6);
  int lane = threadIdx.x & 63;
  const float* x = hs + (size_t)row * 768;
  float v[12];
#pragma unroll
  for (int it = 0; it < 3; ++it) {
    int c = (lane + it * 64) * 4;
    f32x4 d = *(const f32x4*)(x + c);
    v[it * 4 + 0] = d[0]; v[it * 4 + 1] = d[1]; v[it * 4 + 2] = d[2]; v[it * 4 + 3] = d[3];
  }
  float s = 0.f, s2 = 0.f;
#pragma unroll
  for (int i = 0; i < 12; ++i) { s += v[i]; s2 += v[i] * v[i]; }
#pragma unroll
  for (int off = 32; off >= 1; off >>= 1) {
    s += __shfl_xor(s, off, 64);
    s2 += __shfl_xor(s2, off, 64);
  }
  float inv_n = 1.0f / 768.f;
  float mean = s * inv_n;
  float var = fmaxf(s2 * inv_n - mean * mean, 0.f);
  float rstd = rsqrtf(var + 1e-5f);
  if (lane == 0) { rstdg[row] = rstd; mrstdg[row] = mean * rstd; }
#pragma unroll
  for (int it = 0; it < 3; ++it) {
    int c = (lane + it * 64) * 4;
    uint2 po;
    po.x = (uint32_t)f2b(v[it * 4 + 0]) | ((uint32_t)f2b(v[it * 4 + 1]) << 16);
    po.y = (uint32_t)f2b(v[it * 4 + 2]) | ((uint32_t)f2b(v[it * 4 + 3]) << 16);
    *(uint2*)(out + (size_t)row * 768 + c) = po;
  }
}

// --- h = hs + sigmoid(gate)*LN(ao): outputs f32 h, bf16 h, per-row LN stats of h ---
__global__ __launch_bounds__(256) void ln_res(const u16* __restrict__ ao, const float* __restrict__ g,
                                              const float* __restrict__ bta,
                                              const float* __restrict__ hs,
                                              const float* __restrict__ gatep,
                                              float* __restrict__ hf, u16* __restrict__ hb,
                                              float* __restrict__ rstdg, float* __restrict__ mrstdg) {
  int row = blockIdx.x * 4 + (threadIdx.x >> 6);
  int lane = threadIdx.x & 63;
  const u16* xb = ao + (size_t)row * 768;
  float v[12];
#pragma unroll
  for (int it = 0; it < 3; ++it) {
    int c = (lane + it * 64) * 4;
    uint2 d = *(const uint2*)(xb + c);
    v[it * 4 + 0] = b2f(d.x & 0xffff); v[it * 4 + 1] = b2f(d.x >> 16);
    v[it * 4 + 2] = b2f(d.y & 0xffff); v[it * 4 + 3] = b2f(d.y >> 16);
  }
  float s = 0.f, s2 = 0.f;
#pragma unroll
  for (int i = 0; i < 12; ++i) { s += v[i]; s2 += v[i] * v[i]; }
#pragma unroll
  for (int off = 32; off >= 1; off >>= 1) {
    s += __shfl_xor(s, off, 64);
    s2 += __shfl_xor(s2, off, 64);
  }
  float inv_n = 1.0f / 768.f;
  float mean = s * inv_n;
  float var = fmaxf(s2 * inv_n - mean * mean, 0.f);
  float rstd = rsqrtf(var + 1e-5f);
  float gate = 1.f / (1.f + __expf(-gatep[0]));
  float hsum = 0.f, hsum2 = 0.f;
  float o[12];
#pragma unroll
  for (int it = 0; it < 3; ++it) {
    int c = (lane + it * 64) * 4;
    const float* rr = hs + (size_t)row * 768 + c;
#pragma unroll
    for (int i = 0; i < 4; ++i) {
      float hv = rr[i] + gate * ((v[it * 4 + i] - mean) * rstd * g[c + i] + bta[c + i]);
      o[it * 4 + i] = hv;
      hsum += hv; hsum2 += hv * hv;
    }
    *(f32x4*)(hf + (size_t)row * 768 + c) = (f32x4){o[it * 4 + 0], o[it * 4 + 1], o[it * 4 + 2], o[it * 4 + 3]};
    uint2 po;
    po.x = (uint32_t)f2b(o[it * 4 + 0]) | ((uint32_t)f2b(o[it * 4 + 1]) << 16);
    po.y = (uint32_t)f2b(o[it * 4 + 2]) | ((uint32_t)f2b(o[it * 4 + 3]) << 16);
    *(uint2*)(hb + (size_t)row * 768 + c) = po;
  }
#pragma unroll
  for (int off = 32; off >= 1; off >>= 1) {
    hsum += __shfl_xor(hsum, off, 64);
    hsum2 += __shfl_xor(hsum2, off, 64);
  }
  float hm = hsum * inv_n;
  float hvar = fmaxf(hsum2 * inv_n - hm * hm, 0.f);
  float hrstd = rsqrtf(hvar + 1e-5f);
  if (lane == 0) { rstdg[row] = hrstd; mrstdg[row] = hm * hrstd; }
}

// ---------------- MFMA GEMM: C = A(MxK)*BT(NxK)^T, BMx128 tile, BK=32 ----------------
// T3 2-phase: STAGE(next) || ds_read+MFMA(cur); one vmcnt(0)+barrier per step.
// bf16 operands via global_load_lds (linear dest, pre-swizzled source); f32 operands
// reg-staged with swizzled ds_write (BM=128 only). BM in {64,128}.
// AMODE/BMODE: 0 bf16-DMA | 1 f32-reg. EPI: 0 none | 1 +bias |
// 3 LNfold(precomp)+bias | 4 LNfold(in-GEMM stats)+bias | 5 LNfold(precomp)+bias+gelu.
template <int BM, int SPLITK, int AMODE, int BMODE, int EPI, bool OUTF32, bool VTOUT>
__device__ __forceinline__ void gemm_body(const void* __restrict__ Av, const void* __restrict__ Bv,
                                          const float* __restrict__ bias,
                                          const float* __restrict__ rstdg,
                                          const float* __restrict__ mrstdg,
                                          const float* __restrict__ ucol,
                                          const float* __restrict__ wcol,
                                          void* __restrict__ Cv, u16* __restrict__ VTout,
                                          int M, int N, int K) {
  constexpr int MT = BM / 32;   // m-tiles per wave
  constexpr int AL = BM / 64;   // DMA loads per wave for A
  __shared__ __align__(16) u16 aT[2][BM * 32];
  __shared__ __align__(16) u16 bT[2][128 * 32];
  __shared__ float rstd_s[EPI == 4 ? 128 : 1];
  __shared__ float mrstd_s[EPI == 4 ? 128 : 1];
  __shared__ __align__(16) u16 vtile[VTOUT ? 64 * 136 : 1];

  int gx = gridDim.x, gy = gridDim.y;
  int nwg = gx * gy * (int)gridDim.z;
  int lid = ((int)blockIdx.z * gy + (int)blockIdx.y) * gx + (int)blockIdx.x;
  int wid = xcd_swizzle(lid, nwg);
  int bz = wid / (gx * gy);
  int rem = wid - bz * (gx * gy);
  int bx = rem / gy;
  int by = rem - bx * gy;

  int t = threadIdx.x, lane = t & 63, wave = t >> 6;
  int quad = lane >> 4, lcol = lane & 15;
  int wm = (wave >> 1) * (16 * MT), wn = (wave & 1) * 64;
  const u16* Ab = (const u16*)Av;
  const float* Af = (const float*)Av;
  const u16* Bb = (const u16*)Bv;
  const float* Bf = (const float*)Bv;
  const int kchunk = (SPLITK > 1) ? K / SPLITK : K;
  const int kstart = (SPLITK > 1) ? bz * kchunk : 0;
  // f32 reg-stage mapping (BM=128 only): row rr, 16 cols at rc*16
  int rr = t >> 1, rc = t & 1;
  float sa = 0.f, sa2 = 0.f;
  f32x4 acc[MT][4];
#pragma unroll
  for (int i = 0; i < MT; ++i)
#pragma unroll
    for (int j = 0; j < 4; ++j) acc[i][j] = (f32x4){0.f, 0.f, 0.f, 0.f};

  f32x4 araw[4], braw[4];

  auto dmaA = [&](int buf, int k0) {
#pragma unroll
    for (int s2 = 0; s2 < AL; ++s2) {
      int row = (wave * AL + s2) * 16 + (lane >> 2);
      int ch = (lane & 3) ^ (row & 3);
      gload_lds16(Ab + (size_t)(bx * BM + row) * K + kstart + k0 + ch * 8,
                  &aT[buf][(wave * AL + s2) * 512]);
    }
  };
  auto dmaB = [&](int buf, int k0) {
#pragma unroll
    for (int s2 = 0; s2 < 2; ++s2) {
      int row = (wave * 2 + s2) * 16 + (lane >> 2);
      int ch = (lane & 3) ^ (row & 3);
      gload_lds16(Bb + (size_t)(by * 128 + row) * K + kstart + k0 + ch * 8,
                  &bT[buf][(wave * 2 + s2) * 512]);
    }
  };
  auto regloadA = [&](int k0) {
    const f32x4* p = (const f32x4*)&Af[(size_t)(bx * BM + rr) * K + kstart + k0 + rc * 16];
#pragma unroll
    for (int i = 0; i < 4; ++i) araw[i] = p[i];
  };
  auto regstoreA = [&](int buf) {
    if (EPI == 4) {
#pragma unroll
      for (int i = 0; i < 4; ++i)
#pragma unroll
        for (int j = 0; j < 4; ++j) { sa += araw[i][j]; sa2 += araw[i][j] * araw[i][j]; }
    }
    uint4 c0 = pack8(araw[0], araw[1]), c1 = pack8(araw[2], araw[3]);
    *(uint4*)&aT[buf][rr * 32 + (((rc * 2 + 0) ^ (rr & 3)) << 3)] = c0;
    *(uint4*)&aT[buf][rr * 32 + (((rc * 2 + 1) ^ (rr & 3)) << 3)] = c1;
  };
  auto regloadB = [&](int k0) {
    const f32x4* p = (const f32x4*)&Bf[(size_t)(by * 128 + rr) * K + kstart + k0 + rc * 16];
#pragma unroll
    for (int i = 0; i < 4; ++i) braw[i] = p[i];
  };
  auto regstoreB = [&](int buf) {
    uint4 c0 = pack8(braw[0], braw[1]), c1 = pack8(braw[2], braw[3]);
    *(uint4*)&bT[buf][rr * 32 + (((rc * 2 + 0) ^ (rr & 3)) << 3)] = c0;
    *(uint4*)&bT[buf][rr * 32 + (((rc * 2 + 1) ^ (rr & 3)) << 3)] = c1;
  };
  auto stage_load = [&](int buf, int k0) {
    if (AMODE == 1) regloadA(k0); else dmaA(buf, k0);
    if (BMODE == 1) regloadB(k0); else dmaB(buf, k0);
  };
  auto stage_store = [&](int buf) {
    if (AMODE == 1) regstoreA(buf);
    if (BMODE == 1) regstoreB(buf);
  };
  auto compute = [&](int buf) {
    bf16x8 af[MT], bfr[4];
#pragma unroll
    for (int mt = 0; mt < MT; ++mt) {
      int r = wm + mt * 16 + lcol;
      af[mt] = *(const bf16x8*)&aT[buf][r * 32 + (((quad ^ (r & 3))) << 3)];
    }
#pragma unroll
    for (int nt = 0; nt < 4; ++nt) {
      int r = wn + nt * 16 + lcol;
      bfr[nt] = *(const bf16x8*)&bT[buf][r * 32 + (((quad ^ (r & 3))) << 3)];
    }
#pragma unroll
    for (int mt = 0; mt < MT; ++mt)
#pragma unroll
      for (int nt = 0; nt < 4; ++nt)
        acc[mt][nt] = __builtin_amdgcn_mfma_f32_16x16x32_bf16(af[mt], bfr[nt], acc[mt][nt], 0, 0, 0);
  };

  const int nk = kchunk >> 5;
  stage_load(0, 0);
  stage_store(0);
  vm_drain();
  phase_barrier();
  int cur = 0;
  for (int kt = 0; kt < nk; ++kt) {
    bool more = kt + 1 < nk;
    if (more) stage_load(cur ^ 1, (kt + 1) << 5);   // issue early
    compute(cur);                                   // hide latency
    if (more) stage_store(cur ^ 1);                 // reg paths: pack + ds_write late
    vm_drain();
    phase_barrier();
    cur ^= 1;
  }

  if (EPI == 4) {
    float s = sa, s2 = sa2;
    s += __shfl_xor(s, 1, 64);
    s2 += __shfl_xor(s2, 1, 64);
    if ((t & 1) == 0) {
      float inv_n = 1.0f / (float)K;
      float mean = s * inv_n;
      float var = fmaxf(s2 * inv_n - mean * mean, 0.f);
      float rstd = rsqrtf(var + 1e-5f);
      rstd_s[rr] = rstd;
      mrstd_s[rr] = mean * rstd;
    }
    __syncthreads();
  }

  if (VTOUT) {
    // kv: cols 0..63 -> kb[M][64]; cols 64..127 -> LDS transpose -> VT[b][d][j]
    u16* kb = (u16*)Cv;
#pragma unroll
    for (int mt = 0; mt < MT; ++mt) {
#pragma unroll
      for (int nt = 0; nt < 4; ++nt) {
#pragma unroll
        for (int r = 0; r < 4; ++r) {
          int lrow = wm + mt * 16 + quad * 4 + r;
          int row = bx * BM + lrow;
          int col = wn + nt * 16 + lcol;
          float v = rstd_s[lrow] * acc[mt][nt][r] - mrstd_s[lrow] * ucol[col] + wcol[col] + bias[col];
          u16 hv = f2b(v);
          if (wn == 0) kb[(size_t)row * 64 + col] = hv;
          else vtile[(col - 64) * 136 + lrow] = hv;
        }
      }
    }
    __syncthreads();
    int dd = t >> 2, js = (t & 3) * 32;
    int bg = bx >> 5, j0g = (bx & 31) * 128;
    u16* dst = VTout + ((size_t)bg * 64 + dd) * 4096 + j0g + js;
#pragma unroll
    for (int i = 0; i < 4; ++i)
      *(uint4*)(dst + i * 8) = *(const uint4*)&vtile[dd * 136 + js + i * 8];
    return;
  }

  u16* Cb = (u16*)Cv;
  float* Cf = (float*)Cv;
  if (SPLITK > 1) Cf += (size_t)bz * (size_t)M * (size_t)N;
#pragma unroll
  for (int mt = 0; mt < MT; ++mt) {
#pragma unroll
    for (int nt = 0; nt < 4; ++nt) {
#pragma unroll
      for (int r = 0; r < 4; ++r) {
        int lrow = wm + mt * 16 + quad * 4 + r;
        int row = bx * BM + lrow;
        int col = by * 128 + wn + nt * 16 + lcol;
        float v = acc[mt][nt][r];
        if (EPI == 1) v += bias[col];
        if (EPI == 3 || EPI == 5)
          v = rstdg[row] * v - mrstdg[row] * ucol[col] + wcol[col] + bias[col];
        if (EPI == 5) v = 0.5f * v * (1.f + erff(v * 0.70710678118f));
        size_t idx = (size_t)row * N + col;
        if (OUTF32) Cf[idx] = v; else Cb[idx] = f2b(v);
      }
    }
  }
}

// distinct names per call site (rocprof attribution)
#define GEMM_ARGS const void* Av, const void* Bv, const float* bias, const float* rstdg, \
                  const float* mrstdg, const float* ucol, const float* wcol, void* Cv,   \
                  u16* VTout, int M, int N, int K
__global__ __launch_bounds__(256) void gemm_wc(GEMM_ARGS) {
  gemm_body<128, 1, 0, 1, 0, false, false>(Av, Bv, bias, rstdg, mrstdg, ucol, wcol, Cv, VTout, M, N, K);
}
__global__ __launch_bounds__(256) void gemm_kv(GEMM_ARGS) {
  gemm_body<128, 1, 1, 0, 4, false, true>(Av, Bv, bias, rstdg, mrstdg, ucol, wcol, Cv, VTout, M, N, K);
}
__global__ __launch_bounds__(256) void gemm_q(GEMM_ARGS) {
  gemm_body<64, 1, 0, 0, 3, false, false>(Av, Bv, bias, rstdg, mrstdg, ucol, wcol, Cv, VTout, M, N, K);
}
__global__ __launch_bounds__(256) void gemm_o(GEMM_ARGS) {
  gemm_body<64, 1, 0, 0, 1, false, false>(Av, Bv, bias, rstdg, mrstdg, ucol, wcol, Cv, VTout, M, N, K);
}
__global__ __launch_bounds__(256) void gemm_w1(GEMM_ARGS) {
  gemm_body<128, 1, 0, 0, 5, false, false>(Av, Bv, bias, rstdg, mrstdg, ucol, wcol, Cv, VTout, M, N, K);
}
__global__ __launch_bounds__(256) void gemm_w2(GEMM_ARGS) {
  gemm_body<64, 2, 0, 0, 0, true, false>(Av, Bv, bias, rstdg, mrstdg, ucol, wcol, Cv, VTout, M, N, K);
}

// ---------------- split-K merge for W2: out = p0 + p1 + h + b2 ----------------
__global__ __launch_bounds__(256) void w2_merge(const float* __restrict__ part,
                                                const float* __restrict__ hf,
                                                const float* __restrict__ b2,
                                                float* __restrict__ out) {
  int idx = blockIdx.x * 256 + threadIdx.x;
  f32x4 p0 = ((const f32x4*)part)[idx];
  f32x4 p1 = ((const f32x4*)part)[idx + 393216];
  f32x4 h = ((const f32x4*)hf)[idx];
  f32x4 bb = ((const f32x4*)b2)[idx % 192];
  f32x4 o;
#pragma unroll
  for (int i = 0; i < 4; ++i) o[i] = p0[i] + p1[i] + h[i] + bb[i];
  ((f32x4*)out)[idx] = o;
}

// ---------------- flash attention, MQA (NKV=1), HD=64, no-max softmax, j-split=2 ----------------
// dbuf K/V LDS, T14 issue-early/write-late, 1 barrier/jt, cvt_pk P-conversion, setprio.
__global__ __launch_bounds__(256) void attn_kernel(const u16* __restrict__ qbuf,
                                                   const u16* __restrict__ kb,
                                                   const u16* __restrict__ VT,
                                                   float* __restrict__ Opart,
                                                   float* __restrict__ lpart) {
  __shared__ __align__(16) u16 k_lds[2][64 * 72];
  __shared__ __align__(16) u16 vt_lds[2][64 * 72];
  __shared__ __align__(16) u16 p_lds[4 * 16 * 72];
  int lid = ((int)blockIdx.z * 12 + (int)blockIdx.y) * 4 + (int)blockIdx.x;
  int wid = (lid & 7) * 96 + (lid >> 3);
  int bi = wid & 3;
  int h = (wid >> 2) % 12;
  int z = wid / 48;
  int b = z >> 1, s = z & 1;
  int t = threadIdx.x;
  int wave = t >> 6, lane = t & 63, quad = lane >> 4, lcol = lane & 15;
  int i0 = bi * 64 + wave * 16;
  const u16* qrow = qbuf + ((size_t)(b * 256 + i0 + lcol) * 768 + h * 64 + quad * 8);
  bf16x8 qf0 = *(const bf16x8*)qrow;
  bf16x8 qf1 = *(const bf16x8*)(qrow + 32);
  float l_r[4] = {0.f, 0.f, 0.f, 0.f};
  f32x4 oacc[4];
#pragma unroll
  for (int nt = 0; nt < 4; ++nt) oacc[nt] = (f32x4){0.f, 0.f, 0.f, 0.f};
  int sr = t >> 2, sc = (t & 3) * 16;
  const u16* kbase = kb + (size_t)b * 4096 * 64;
  const u16* vtbase = VT + (size_t)b * 64 * 4096;
  u16* pw = &p_lds[wave * 16 * 72];

  uint4 kr0, kr1, vr0, vr1;  // staging regs (T14)
  auto stage_load = [&](int jt) {
    int j0 = s * 2048 + jt * 64;
    const u16* krow = kbase + (size_t)(j0 + sr) * 64 + sc;
    kr0 = *(const uint4*)(krow);
    kr1 = *(const uint4*)(krow + 8);
    const u16* vrow = vtbase + (size_t)sr * 4096 + j0 + sc;
    vr0 = *(const uint4*)(vrow);
    vr1 = *(const uint4*)(vrow + 8);
  };
  auto stage_store = [&](int buf) {
    *(uint4*)&k_lds[buf][sr * 72 + sc] = kr0;
    *(uint4*)&k_lds[buf][sr * 72 + sc + 8] = kr1;
    *(uint4*)&vt_lds[buf][sr * 72 + sc] = vr0;
    *(uint4*)&vt_lds[buf][sr * 72 + sc + 8] = vr1;
  };

  stage_load(0);
  stage_store(0);
  phase_barrier();
  int cur = 0;
  for (int jt = 0; jt < 32; ++jt) {
    bool more = jt + 1 < 32;
    if (more) stage_load(jt + 1);  // issue early: latency hides under QK^T+softmax+PV

    f32x4 sc4[4];
#pragma unroll
    for (int nt = 0; nt < 4; ++nt) sc4[nt] = (f32x4){0.f, 0.f, 0.f, 0.f};
    __builtin_amdgcn_s_setprio(1);
#pragma unroll
    for (int nt = 0; nt < 4; ++nt) {
      bf16x8 kb0 = *(const bf16x8*)&k_lds[cur][(nt * 16 + lcol) * 72 + quad * 8];
      bf16x8 kb1 = *(const bf16x8*)&k_lds[cur][(nt * 16 + lcol) * 72 + 32 + quad * 8];
      sc4[nt] = __builtin_amdgcn_mfma_f32_16x16x32_bf16(qf0, kb0, sc4[nt], 0, 0, 0);
      sc4[nt] = __builtin_amdgcn_mfma_f32_16x16x32_bf16(qf1, kb1, sc4[nt], 0, 0, 0);
    }
    __builtin_amdgcn_s_setprio(0);
#pragma unroll
    for (int r = 0; r < 4; ++r) {
      float rsum = 0.f;
#pragma unroll
      for (int nt = 0; nt < 4; ++nt) {
        float p = __expf(sc4[nt][r] * 0.125f);
        sc4[nt][r] = p;
        rsum += p;
      }
      rsum += __shfl_xor(rsum, 1, 64);
      rsum += __shfl_xor(rsum, 2, 64);
      rsum += __shfl_xor(rsum, 4, 64);
      rsum += __shfl_xor(rsum, 8, 64);
      l_r[r] += rsum;
      uint32_t pk01 = cvt_pk_bf16(sc4[0][r], sc4[1][r]);
      uint32_t pk23 = cvt_pk_bf16(sc4[2][r], sc4[3][r]);
      int prow = (quad * 4 + r) * 72 + lcol;
      pw[prow] = (u16)(pk01 & 0xffff);
      pw[prow + 16] = (u16)(pk01 >> 16);
      pw[prow + 32] = (u16)(pk23 & 0xffff);
      pw[prow + 48] = (u16)(pk23 >> 16);
    }
    __builtin_amdgcn_s_setprio(1);
#pragma unroll
    for (int ks = 0; ks < 2; ++ks) {
      bf16x8 pa = *(const bf16x8*)&pw[lcol * 72 + ks * 32 + quad * 8];
#pragma unroll
      for (int nt = 0; nt < 4; ++nt) {
        bf16x8 vb = *(const bf16x8*)&vt_lds[cur][(nt * 16 + lcol) * 72 + ks * 32 + quad * 8];
        oacc[nt] = __builtin_amdgcn_mfma_f32_16x16x32_bf16(pa, vb, oacc[nt], 0, 0, 0);
      }
    }
    __builtin_amdgcn_s_setprio(0);
    if (more) stage_store(cur ^ 1);  // write late (vmcnt auto-waited on reg deps)
    phase_barrier();
    cur ^= 1;
  }
  size_t base = ((size_t)z * 12 + h) * 256;
#pragma unroll
  for (int r = 0; r < 4; ++r) {
    int row = bi * 64 + wave * 16 + quad * 4 + r;
#pragma unroll
    for (int nt = 0; nt < 4; ++nt)
      Opart[(base + row) * 64 + nt * 16 + lcol] = oacc[nt][r];
    if (lcol == 0) lpart[base + row] = l_r[r];
  }
}

// ---------------- merge j-split partials -> attn_o bf16 ----------------
__global__ __launch_bounds__(256) void attn_merge(const float* __restrict__ Opart,
                                                  const float* __restrict__ lpart,
                                                  u16* __restrict__ attn_o) {
  int row = blockIdx.x;
  int col = blockIdx.y * 256 + threadIdx.x;
  int b = row >> 8, i = row & 255, h = col >> 6, d = col & 63;
  size_t i0 = (((size_t)(b * 2 + 0) * 12 + h) * 256 + i);
  size_t i1 = (((size_t)(b * 2 + 1) * 12 + h) * 256 + i);
  float o = Opart[i0 * 64 + d] + Opart[i1 * 64 + d];
  float l = lpart[i0] + lpart[i1];
  attn_o[(size_t)row * 768 + col] = f2b(o / l);
}

// ---------------- launch ----------------
extern "C" void kernel_launch(void* const* d_in, const int* in_sizes, int n_in, void* d_out,
                              int out_size, void* d_ws, size_t ws_size, hipStream_t stream) {
  (void)in_sizes; (void)n_in; (void)out_size; (void)ws_size;
  const float* hs = (const float*)d_in[0];
  const float* imgf = (const float*)d_in[1];
  const float* ln_img_g = (const float*)d_in[2];
  const float* ln_img_b = (const float*)d_in[3];
  const float* W_bottle = (const float*)d_in[4];
  const float* ln_h_g = (const float*)d_in[5];
  const float* ln_h_b = (const float*)d_in[6];
  const float* Wq = (const float*)d_in[7];
  const float* bq = (const float*)d_in[8];
  const float* Wkv = (const float*)d_in[9];
  const float* bkv = (const float*)d_in[10];
  const float* Wo = (const float*)d_in[11];
  const float* bo = (const float*)d_in[12];
  const float* ln_ao_g = (const float*)d_in[13];
  const float* ln_ao_b = (const float*)d_in[14];
  const float* gatep = (const float*)d_in[15];
  const float* ln_f_g = (const float*)d_in[16];
  const float* ln_f_b = (const float*)d_in[17];
  const float* W1 = (const float*)d_in[18];
  const float* b1 = (const float*)d_in[19];
  const float* W2 = (const float*)d_in[20];
  const float* b2 = (const float*)d_in[21];

  char* sc = (char*)d_ws;
  auto alloc = [&](size_t bytes) {
    char* p = sc;
    sc += (bytes + 63) & ~(size_t)63;
    return p;
  };
  u16* WTq = (u16*)alloc(768 * 768 * 2);
  u16* WTo = (u16*)alloc(768 * 768 * 2);
  u16* WT1 = (u16*)alloc(3072 * 768 * 2);
  u16* WT2 = (u16*)alloc(768 * 3072 * 2);
  u16* WkvT = (u16*)alloc(128 * 768 * 2);
  u16* WcT = (u16*)alloc(128 * 1024 * 2);
  u16* WgT = (u16*)alloc(128 * 1024 * 2);
  u16* WqgT = (u16*)alloc(768 * 768 * 2);
  u16* W1gT = (u16*)alloc(3072 * 768 * 2);
  float* ucol = (float*)alloc(128 * 4);
  float* wcol = (float*)alloc(128 * 4);
  float* uq = (float*)alloc(768 * 4);
  float* wq = (float*)alloc(768 * 4);
  float* u1 = (float*)alloc(3072 * 4);
  float* w1c = (float*)alloc(3072 * 4);
  float* rstdq = (float*)alloc(2048 * 4);
  float* mrstdq = (float*)alloc(2048 * 4);
  float* rstdh = (float*)alloc(2048 * 4);
  float* mrstdh = (float*)alloc(2048 * 4);
  u16* hs16 = (u16*)alloc(2048 * 768 * 2);
  u16* kb = (u16*)alloc((size_t)32768 * 64 * 2);
  u16* VT = (u16*)alloc((size_t)8 * 64 * 4096 * 2);
  u16* qb = (u16*)alloc(2048 * 768 * 2);
  u16* attn_o = (u16*)alloc(2048 * 768 * 2);
  u16* ao = (u16*)alloc(2048 * 768 * 2);
  u16* hbuf = (u16*)alloc(2048 * 768 * 2);
  float* hf32 = (float*)alloc(2048 * 768 * 4);
  u16* actb = (u16*)alloc((size_t)2048 * 3072 * 2);
  float* Opart = (float*)alloc((size_t)16 * 12 * 256 * 64 * 4);  // also W2 split-K partials
  float* lpart = (float*)alloc((size_t)16 * 12 * 256 * 4);

  // weight transposes (f32 -> bf16, (N,K) layout)
  transpose_f2b<<<dim3(24, 24), 256, 0, stream>>>(Wq, WTq, 768, 768);
  transpose_f2b<<<dim3(24, 24), 256, 0, stream>>>(Wo, WTo, 768, 768);
  transpose_f2b<<<dim3(96, 24), 256, 0, stream>>>(W1, WT1, 768, 3072);
  transpose_f2b<<<dim3(24, 96), 256, 0, stream>>>(W2, WT2, 3072, 768);
  transpose_f2b<<<dim3(4, 24), 256, 0, stream>>>(Wkv, WkvT, 768, 128);

  // WcT[n,kimg] = sum_j WkvT[n,j] * W_bottle[kimg,j]  (B f32 reg-staged)
  gemm_wc<<<dim3(1, 8), 256, 0, stream>>>(WkvT, W_bottle, nullptr, nullptr, nullptr, nullptr,
                                          nullptr, WcT, nullptr, 128, 1024, 768);
  // LN-fold weight preps
  prep_wg<<<32, 256, 0, stream>>>(WcT, ln_img_g, ln_img_b, WgT, ucol, wcol, 1024);
  prep_wg<<<192, 256, 0, stream>>>(WTq, ln_h_g, ln_h_b, WqgT, uq, wq, 768);
  prep_wg<<<768, 256, 0, stream>>>(WT1, ln_f_g, ln_f_b, W1gT, u1, w1c, 768);
  // hs -> bf16 + LN stats (for folded q)
  hs_prep<<<512, 256, 0, stream>>>(hs, hs16, rstdq, mrstdq);
  // kv (fused img-LN, in-GEMM stats from f32 A) -> kb + VT
  gemm_kv<<<dim3(256, 1), 256, 0, stream>>>(imgf, WgT, bkv, nullptr, nullptr, ucol, wcol,
                                            kb, VT, 32768, 128, 1024);
  // q = LN(hs) @ Wq + bq  (folded, precomputed stats)
  gemm_q<<<dim3(32, 6), 256, 0, stream>>>(hs16, WqgT, bq, rstdq, mrstdq, uq, wq,
                                          qb, nullptr, 2048, 768, 768);
  // attention (j-split=2) + merge
  attn_kernel<<<dim3(4, 12, 16), 256, 0, stream>>>(qb, kb, VT, Opart, lpart);
  attn_merge<<<dim3(2048, 3), 256, 0, stream>>>(Opart, lpart, attn_o);
  // out proj
  gemm_o<<<dim3(32, 6), 256, 0, stream>>>(attn_o, WTo, bo, nullptr, nullptr, nullptr, nullptr,
                                          ao, nullptr, 2048, 768, 768);
  // h = hs + sigmoid(gate)*LN(ao): f32 + bf16 + h-stats
  ln_res<<<512, 256, 0, stream>>>(ao, ln_ao_g, ln_ao_b, hs, gatep, hf32, hbuf, rstdh, mrstdh);
  // act = gelu(LN(h) @ W1 + b1)  (folded, precomputed stats)
  gemm_w1<<<dim3(16, 24), 256, 0, stream>>>(hbuf, W1gT, b1, rstdh, mrstdh, u1, w1c,
                                            actb, nullptr, 2048, 3072, 768);
  // W2 split-K=2 partials into Opart, then merge with h + b2
  gemm_w2<<<dim3(32, 6, 2), 256, 0, stream>>>(actb, WT2, nullptr, nullptr, nullptr, nullptr, nullptr,
                                              Opart, nullptr, 2048, 768, 3072);
  w2_merge<<<1536, 256, 0, stream>>>(Opart, hf32, b2, (float*)d_out);
}